// Round 1
// baseline (661.094 us; speedup 1.0000x reference)
//
#include <hip/hip_runtime.h>
#include <math.h>

#define S_TOT   2048
#define NNODES  128
#define D_DIM   127
#define N_STEPS 126
#define LAM_MAX 0.06f
#define EPS_P   1e-7f

__device__ __forceinline__ float softplus_f(float x) {
    return log1pf(expf(-fabsf(x))) + fmaxf(x, 0.0f);
}
__device__ __forceinline__ float normal_cdf_f(float x) {
    return 0.5f * (1.0f + erff(x * 0.7071067811865475f));
}

// ---------------------------------------------------------------------------
// Kernel 1: trajectory construction. One wave (64 threads) per sample.
// Lane l holds elements l and l+64 of the D=127 vectors.
// Writes x as [S][128 rows][127 dims] fp32 into workspace.
// ---------------------------------------------------------------------------
__global__ __launch_bounds__(64) void traj_kernel(
        const float* __restrict__ d_raw,   // [S][127]
        const float* __restrict__ c_raw,   // [S][126]
        const float* __restrict__ a_raw,   // [S][126][127]
        float* __restrict__ xout,          // [S][128][127]
        int s_base) {
    const int s    = s_base + blockIdx.x;
    const int lane = threadIdx.x;
    const bool hi_ok = (lane + 64) < D_DIM;   // lane < 63

    // softplus(d) preloaded; broadcast later via shuffles
    float dlo = softplus_f(d_raw[(size_t)s * D_DIM + lane]);
    float dhi = hi_ok ? softplus_f(d_raw[(size_t)s * D_DIM + lane + 64]) : 0.0f;

    // v = e0, x1 = d0 * e0
    float v0 = (lane == 0) ? 1.0f : 0.0f;
    float v1 = 0.0f;
    const float d_first = __shfl(dlo, 0);
    float x0 = d_first * v0;
    float x1 = 0.0f;

    float* xrow = xout + (size_t)s * NNODES * D_DIM;
    // row 0: zeros
    xrow[lane] = 0.0f;
    if (hi_ok) xrow[lane + 64] = 0.0f;
    // row 1
    xrow += D_DIM;
    xrow[lane] = x0;
    if (hi_ok) xrow[lane + 64] = x1;

    const float* arow = a_raw + (size_t)s * N_STEPS * D_DIM;
    // prefetch a row 0
    float a0r = arow[lane];
    float a1r = hi_ok ? arow[lane + 64] : 0.0f;

    for (int i = 0; i < N_STEPS; ++i) {
        const float ca = a0r, cb = a1r;
        if (i + 1 < N_STEPS) {                 // software prefetch next row
            const float* nrow = arow + (size_t)(i + 1) * D_DIM;
            a0r = nrow[lane];
            a1r = hi_ok ? nrow[lane + 64] : 0.0f;
        }

        // fused 3-value wave reduction: va = v.a, n2 = v.v, aa = a.a
        float va = v0 * ca + v1 * cb;
        float n2 = v0 * v0 + v1 * v1;
        float aa = ca * ca + cb * cb;
        #pragma unroll
        for (int off = 32; off > 0; off >>= 1) {
            va += __shfl_down(va, off);
            n2 += __shfl_down(n2, off);
            aa += __shfl_down(aa, off);
        }
        va = __shfl(va, 0); n2 = __shfl(n2, 0); aa = __shfl(aa, 0);

        const float vE0 = __shfl(v0, 0), vE1 = __shfl(v0, 1);
        const float aE0 = __shfl(ca, 0), aE1 = __shfl(ca, 1);

        // LAPACK Householder QR sign convention for Q[:,1]:
        //   s_ = sign(v0) (Fortran SIGN: +1 at 0), n = ||v||
        //   u.a = a0 + (v.a - v0*a0)/(v0 + s_*n)
        //   w1  = a1 - (u.a)*v1/(s_*n)
        //   a_orth = -sign(w1) * a_perp / ||a_perp||
        const float n   = sqrtf(n2);
        const float s_  = (vE0 >= 0.0f) ? 1.0f : -1.0f;
        const float ua  = aE0 + (va - vE0 * aE0) / (vE0 + s_ * n);
        const float w1  = aE1 - ua * vE1 / (s_ * n);
        const float sgn = (w1 >= 0.0f) ? -1.0f : 1.0f;

        const float pscale = va / n2;
        const float p0 = ca - pscale * v0;
        const float p1 = cb - pscale * v1;
        const float perp2 = aa - va * va / n2;
        const float inv = sgn / sqrtf(perp2);

        const float ci = c_raw[(size_t)s * N_STEPS + i];
        const float cosc = cosf(ci), sinc = sinf(ci);
        const float sf = sinc * inv;

        v0 = cosc * v0 + sf * p0;
        v1 = cosc * v1 + sf * p1;

        const int di = i + 1;
        const float dstep = (di < 64) ? __shfl(dlo, di) : __shfl(dhi, di - 64);
        x0 += dstep * v0;
        x1 += dstep * v1;

        xrow += D_DIM;
        xrow[lane] = x0;
        if (hi_ok) xrow[lane + 64] = x1;
    }
}

// ---------------------------------------------------------------------------
// Kernel 2: pairwise dists + log-likelihood per sample. One block per sample.
// LDS: xT[k][n] (k=dim 0..126, n=node 0..127), pad 129 -> conflict-free.
// 256 threads, each computes an 8x8 strided tile of the 128x128 pair matrix.
// ---------------------------------------------------------------------------
#define K2_THREADS 256
__global__ __launch_bounds__(K2_THREADS) void ll_kernel(
        const float* __restrict__ xin,     // [S][128][127]
        const float* __restrict__ l_raw,   // [S][1]
        const int*   __restrict__ all_t,   // [128][128]
        const int*   __restrict__ cor_t,   // [128][128]
        float* __restrict__ sums,          // [S]
        int s_base) {
    const int s = s_base + blockIdx.x;
    const int t = threadIdx.x;

    __shared__ float xT[D_DIM][129];
    __shared__ float sqv[NNODES];
    __shared__ float wsum[4];

    // load + transpose: global coalesced, LDS stride-129 writes conflict-free
    const float* gx = xin + (size_t)s * NNODES * D_DIM;
    for (int idx = t; idx < NNODES * D_DIM; idx += K2_THREADS) {
        const int row = idx / D_DIM;
        const int k   = idx - row * D_DIM;
        xT[k][row] = gx[idx];
    }
    __syncthreads();

    // squared norms per node
    if (t < NNODES) {
        float s2 = 0.0f;
        #pragma unroll 4
        for (int k = 0; k < D_DIM; ++k) { const float v = xT[k][t]; s2 += v * v; }
        sqv[t] = s2;
    }
    __syncthreads();

    // 8x8 tile per thread, stride 16 in both n and m
    const int tm = t & 15;
    const int tn = t >> 4;

    float acc[8][8];
    #pragma unroll
    for (int i = 0; i < 8; ++i)
        #pragma unroll
        for (int j = 0; j < 8; ++j) acc[i][j] = 0.0f;

    for (int k = 0; k < D_DIM; ++k) {
        float xn[8], xm[8];
        #pragma unroll
        for (int i = 0; i < 8; ++i) xn[i] = xT[k][tn + 16 * i];
        #pragma unroll
        for (int j = 0; j < 8; ++j) xm[j] = xT[k][tm + 16 * j];
        #pragma unroll
        for (int i = 0; i < 8; ++i)
            #pragma unroll
            for (int j = 0; j < 8; ++j) acc[i][j] += xn[i] * xm[j];
    }

    // epilogue: p_axb = 0.5*(1 + erf(pd/2)*erf(pd/(2*sqrt2)))
    const float lam = LAM_MAX * normal_cdf_f(l_raw[s]);
    const float one_m2l = 1.0f - 2.0f * lam;
    const float pmin = EPS_P, pmax = 1.0f - EPS_P;

    float llsum = 0.0f;
    #pragma unroll
    for (int i = 0; i < 8; ++i) {
        const int nn = tn + 16 * i;
        const float sqn = sqv[nn];
        #pragma unroll
        for (int j = 0; j < 8; ++j) {
            const int mm = tm + 16 * j;
            const float d2 = fmaxf(sqn + sqv[mm] - 2.0f * acc[i][j], 0.0f);
            const float pd = sqrtf(d2);
            const float A = erff(pd * 0.5f);
            const float B = erff(pd * 0.3535533905932738f);
            float p = one_m2l * (0.5f + 0.5f * A * B) + lam;
            p = fminf(fmaxf(p, pmin), pmax);
            const float ncor = (float)cor_t[nn * NNODES + mm];
            const float nall = (float)all_t[nn * NNODES + mm];
            llsum += ncor * logf(p) + (nall - ncor) * log1pf(-p);
        }
    }

    // block reduction (wave shuffle + LDS)
    #pragma unroll
    for (int off = 32; off > 0; off >>= 1) llsum += __shfl_down(llsum, off);
    const int lane = t & 63, wid = t >> 6;
    if (lane == 0) wsum[wid] = llsum;
    __syncthreads();
    if (t == 0) sums[s] = wsum[0] + wsum[1] + wsum[2] + wsum[3];
}

// ---------------------------------------------------------------------------
// Kernel 3: deterministic final reduction: mean over S
// ---------------------------------------------------------------------------
__global__ __launch_bounds__(256) void reduce_kernel(
        const float* __restrict__ sums, float* __restrict__ out) {
    __shared__ double sh[256];
    const int t = threadIdx.x;
    double acc = 0.0;
    for (int i = t; i < S_TOT; i += 256) acc += (double)sums[i];
    sh[t] = acc;
    __syncthreads();
    for (int off = 128; off > 0; off >>= 1) {
        if (t < off) sh[t] += sh[t + off];
        __syncthreads();
    }
    if (t == 0) out[0] = (float)(sh[0] / (double)S_TOT);
}

// ---------------------------------------------------------------------------
extern "C" void kernel_launch(void* const* d_in, const int* in_sizes, int n_in,
                              void* d_out, int out_size, void* d_ws, size_t ws_size,
                              hipStream_t stream) {
    (void)in_sizes; (void)n_in; (void)out_size;
    const float* d_raw = (const float*)d_in[0];
    const float* c_raw = (const float*)d_in[1];
    const float* a_raw = (const float*)d_in[2];
    const float* l_raw = (const float*)d_in[3];
    const int*   all_t = (const int*)d_in[4];
    const int*   cor_t = (const int*)d_in[5];
    float* out = (float*)d_out;

    char*  ws   = (char*)d_ws;
    float* sums = (float*)ws;                       // S_TOT floats = 8 KB
    float* xbuf = (float*)(ws + 8192);
    const size_t xbytes_per = (size_t)NNODES * D_DIM * sizeof(float); // 65024 B

    size_t avail = (ws_size > 8192) ? ws_size - 8192 : 0;
    int chunk = (int)(avail / xbytes_per);
    if (chunk > S_TOT) chunk = S_TOT;
    if (chunk < 1) chunk = 1;

    for (int s0 = 0; s0 < S_TOT; s0 += chunk) {
        const int nblk = (S_TOT - s0 < chunk) ? (S_TOT - s0) : chunk;
        traj_kernel<<<nblk, 64, 0, stream>>>(d_raw, c_raw, a_raw, xbuf, s0);
        ll_kernel<<<nblk, K2_THREADS, 0, stream>>>(xbuf, l_raw, all_t, cor_t, sums, s0);
    }
    reduce_kernel<<<1, 256, 0, stream>>>(sums, out);
}

// Round 2
// 329.169 us; speedup vs baseline: 2.0084x; 2.0084x over previous
//
#include <hip/hip_runtime.h>
#include <math.h>

#define S_TOT   2048
#define NNODES  128
#define D_DIM   127
#define N_STEPS 126
#define KPAD    128

typedef unsigned short ushort_t;
typedef unsigned int   uint_t;
typedef __attribute__((ext_vector_type(8))) short bfrag;   // 8 bf16 = 4 VGPR
typedef __attribute__((ext_vector_type(4))) float f4;

__device__ __forceinline__ float softplus_f(float x) {
    return log1pf(expf(-fabsf(x))) + fmaxf(x, 0.0f);
}
__device__ __forceinline__ float normal_cdf_f(float x) {
    return 0.5f * (1.0f + erff(x * 0.7071067811865475f));
}
__device__ __forceinline__ float frl(float x, int lane) {
    return __int_as_float(__builtin_amdgcn_readlane(__float_as_int(x), lane));
}
// 64-lane sum via DPP (classic gfx9 sequence); returns wave-uniform total.
__device__ __forceinline__ float wave_sum(float x) {
    float r = x; int v;
    v = __builtin_amdgcn_update_dpp(0, __float_as_int(r), 0x111, 0xf, 0xf, true); r += __int_as_float(v);
    v = __builtin_amdgcn_update_dpp(0, __float_as_int(r), 0x112, 0xf, 0xf, true); r += __int_as_float(v);
    v = __builtin_amdgcn_update_dpp(0, __float_as_int(r), 0x114, 0xf, 0xf, true); r += __int_as_float(v);
    v = __builtin_amdgcn_update_dpp(0, __float_as_int(r), 0x118, 0xf, 0xf, true); r += __int_as_float(v);
    v = __builtin_amdgcn_update_dpp(0, __float_as_int(r), 0x142, 0xa, 0xf, true); r += __int_as_float(v);
    v = __builtin_amdgcn_update_dpp(0, __float_as_int(r), 0x143, 0xc, 0xf, true); r += __int_as_float(v);
    return frl(r, 63);
}
__device__ __forceinline__ ushort_t f2bf(float x) {        // RNE fp32 -> bf16
    uint_t u = __float_as_uint(x);
    uint_t r = u + 0x7fffu + ((u >> 16) & 1u);
    return (ushort_t)(r >> 16);
}
__device__ __forceinline__ float bf2f(ushort_t h) {
    return __uint_as_float(((uint_t)h) << 16);
}

// ---------------------------------------------------------------------------
// Kernel 0: symmetrized count tables as floats.
// ---------------------------------------------------------------------------
__global__ __launch_bounds__(256) void prep_counts(
        const int* __restrict__ all_t, const int* __restrict__ cor_t,
        float* __restrict__ asym, float* __restrict__ csym) {
    int i = blockIdx.x * 256 + threadIdx.x;       // 16384
    int n = i >> 7, m = i & 127;
    int at = all_t[i], ct = cor_t[i];
    if (n != m) { at += all_t[m * 128 + n]; ct += cor_t[m * 128 + n]; }
    asym[i] = (float)at; csym[i] = (float)ct;
}

// ---------------------------------------------------------------------------
// Kernel 1: trajectory. One wave per sample; lane l owns dims l, l+64.
// Emits x as bf16 hi/lo pair, [chunk][128 nodes][128 k] (k=127 zero-padded).
// ---------------------------------------------------------------------------
__global__ __launch_bounds__(64) void traj_kernel(
        const float* __restrict__ d_raw, const float* __restrict__ c_raw,
        const float* __restrict__ a_raw,
        ushort_t* __restrict__ xhi, ushort_t* __restrict__ xlo,
        int s_base) {
    const int li = blockIdx.x;
    const int s  = s_base + li;
    const int lane = threadIdx.x;
    const bool hi_ok = lane < 63;                 // dim 64+lane valid

    float dlo = softplus_f(d_raw[(size_t)s * D_DIM + lane]);
    float dhi = hi_ok ? softplus_f(d_raw[(size_t)s * D_DIM + 64 + lane]) : 0.0f;
    float clo = (lane < 126) ? c_raw[(size_t)s * N_STEPS + lane] : 0.0f;
    float chi = (lane < 62)  ? c_raw[(size_t)s * N_STEPS + 64 + lane] : 0.0f;

    float v0 = (lane == 0) ? 1.0f : 0.0f, v1 = 0.0f;
    float x0 = frl(dlo, 0) * v0, x1 = 0.0f;

    ushort_t* hrow = xhi + (size_t)li * NNODES * KPAD;
    ushort_t* lrow = xlo + (size_t)li * NNODES * KPAD;
    hrow[lane] = 0; hrow[64 + lane] = 0; lrow[lane] = 0; lrow[64 + lane] = 0;
    hrow += KPAD; lrow += KPAD;
    {
        float xb = hi_ok ? x1 : 0.0f;
        ushort_t h0 = f2bf(x0), h1 = f2bf(xb);
        hrow[lane] = h0; hrow[64 + lane] = h1;
        lrow[lane] = f2bf(x0 - bf2f(h0)); lrow[64 + lane] = f2bf(xb - bf2f(h1));
    }

    const float* arow = a_raw + (size_t)s * N_STEPS * D_DIM;
    float a0r = arow[lane];
    float a1r = hi_ok ? arow[64 + lane] : 0.0f;

    for (int i = 0; i < N_STEPS; ++i) {
        const float ca = a0r, cb = a1r;
        if (i + 1 < N_STEPS) {
            const float* nr = arow + (size_t)(i + 1) * D_DIM;
            a0r = nr[lane];
            a1r = hi_ok ? nr[64 + lane] : 0.0f;
        }
        float va = v0 * ca + v1 * cb;
        float aa = ca * ca + cb * cb;
        va = wave_sum(va);
        aa = wave_sum(aa);

        const float vE0 = frl(v0, 0), vE1 = frl(v0, 1);
        const float aE0 = frl(ca, 0), aE1 = frl(ca, 1);
        // LAPACK Householder sign (||v|| == 1 by construction):
        const float s_  = (vE0 >= 0.0f) ? 1.0f : -1.0f;
        const float ua  = aE0 + (va - vE0 * aE0) * __builtin_amdgcn_rcpf(vE0 + s_);
        const float w1  = aE1 - ua * vE1 * s_;           // 1/s_ == s_
        const float sgn = (w1 >= 0.0f) ? -1.0f : 1.0f;
        const float perp2 = aa - va * va;
        const float inv = sgn * __builtin_amdgcn_rsqf(perp2);

        const float ci = (i < 64) ? frl(clo, i) : frl(chi, i - 64);
        const float cosc = __cosf(ci), sinc = __sinf(ci);
        const float sf = sinc * inv;

        v0 = cosc * v0 + sf * (ca - va * v0);
        v1 = cosc * v1 + sf * (cb - va * v1);

        const int di = i + 1;
        const float dstep = (di < 64) ? frl(dlo, di) : frl(dhi, di - 64);
        x0 += dstep * v0;
        x1 += dstep * v1;

        hrow += KPAD; lrow += KPAD;
        const float xb = hi_ok ? x1 : 0.0f;
        ushort_t h0 = f2bf(x0), h1 = f2bf(xb);
        hrow[lane] = h0; hrow[64 + lane] = h1;
        lrow[lane] = f2bf(x0 - bf2f(h0)); lrow[64 + lane] = f2bf(xb - bf2f(h1));
    }
}

// ---------------------------------------------------------------------------
// Kernel 2: MFMA gram + log-lik. One block (4 waves, 256 thr) per sample.
// Wave w owns tile-rows {w, 7-w} (9 upper-triangle 16x16 tiles each).
// ---------------------------------------------------------------------------
__device__ __forceinline__ bfrag ldfrag(const ushort_t* base, int row, int kelem) {
    int byte = ((row << 8) + (kelem << 1)) ^ ((row & 7) << 4);
    return *(const bfrag*)((const char*)base + byte);
}
#define MFMA3(acch, accv, ah, al, bh, bl)                                    \
    accv = __builtin_amdgcn_mfma_f32_16x16x32_bf16(ah, bh, accv, 0, 0, 0);   \
    accv = __builtin_amdgcn_mfma_f32_16x16x32_bf16(ah, bl, accv, 0, 0, 0);   \
    accv = __builtin_amdgcn_mfma_f32_16x16x32_bf16(al, bh, accv, 0, 0, 0);

__device__ __forceinline__ float tile_ll(f4 acc, int TR, int TC, int lg, int lr,
        const float* sq, const float* __restrict__ csym,
        const float* __restrict__ asym, float lam, float one_m2l) {
    float sum = 0.0f;
    #pragma unroll
    for (int q = 0; q < 4; ++q) {
        const int n = TR * 16 + 4 * lg + q;
        const int m = TC * 16 + lr;
        const bool take = (TR != TC) || (4 * lg + q <= lr);
        if (take) {
            float d2 = fmaxf(sq[n] + sq[m] - 2.0f * acc[q], 0.0f);
            float pd = __builtin_amdgcn_sqrtf(d2);
            float A = erff(0.5f * pd);
            float B = erff(0.35355339059327373f * pd);
            float pab = fmaf(0.5f * A, B, 0.5f);
            float p  = fmaf(one_m2l, pab, lam);
            float qq = fmaf(-one_m2l, pab, one_m2l + lam);
            p  = fminf(fmaxf(p,  1e-7f), 1.0f - 1e-7f);
            qq = fminf(fmaxf(qq, 1e-7f), 1.0f - 1e-7f);
            const float c = csym[n * 128 + m];
            const float a = asym[n * 128 + m];
            sum += c * __logf(p) + (a - c) * __logf(qq);
        }
    }
    return sum;
}

__global__ __launch_bounds__(256) void ll_kernel(
        const ushort_t* __restrict__ xhi_g, const ushort_t* __restrict__ xlo_g,
        const float* __restrict__ l_raw,
        const float* __restrict__ csym, const float* __restrict__ asym,
        float* __restrict__ sums, int s_base) {
    const int li = blockIdx.x;
    const int s  = s_base + li;
    const int t  = threadIdx.x;

    __shared__ ushort_t Hs[NNODES * KPAD];
    __shared__ ushort_t Ls[NNODES * KPAD];
    __shared__ float sq[NNODES];
    __shared__ float wsum[4];

    // fill LDS (swizzled) from global bf16, 16B chunks
    {
        const uint4* gh = (const uint4*)(xhi_g + (size_t)li * NNODES * KPAD);
        const uint4* gl = (const uint4*)(xlo_g + (size_t)li * NNODES * KPAD);
        for (int i = t; i < NNODES * KPAD / 8; i += 256) {
            const int row = i >> 4;
            const int byte = ((row << 8) + ((i & 15) << 4)) ^ ((row & 7) << 4);
            *(uint4*)((char*)Hs + byte) = gh[i];
            *(uint4*)((char*)Ls + byte) = gl[i];
        }
    }
    __syncthreads();

    const int l  = t & 63, w = t >> 6;
    const int lr = l & 15, lg = l >> 4;
    const int wa = w, wb = 7 - w;

    f4 acc_a[8], acc_b[8];
    #pragma unroll
    for (int i = 0; i < 8; ++i) { acc_a[i] = (f4)(0.0f); acc_b[i] = (f4)(0.0f); }

    #pragma unroll
    for (int ks = 0; ks < 4; ++ks) {
        const int kb = ks * 32 + lg * 8;
        const bfrag ahi_a = ldfrag(Hs, wa * 16 + lr, kb);
        const bfrag alo_a = ldfrag(Ls, wa * 16 + lr, kb);
        const bfrag ahi_b = ldfrag(Hs, wb * 16 + lr, kb);
        const bfrag alo_b = ldfrag(Ls, wb * 16 + lr, kb);
        #pragma unroll
        for (int TC = 0; TC < 8; ++TC) {
            if (TC < wa) continue;                       // wave-uniform
            const bfrag bhi = ldfrag(Hs, TC * 16 + lr, kb);
            const bfrag blo = ldfrag(Ls, TC * 16 + lr, kb);
            MFMA3(, acc_a[TC], ahi_a, alo_a, bhi, blo);
            if (TC >= wb) { MFMA3(, acc_b[TC], ahi_b, alo_b, bhi, blo); }
        }
    }

    // squared norms from gram diagonal (tiles (wa,wa) and (wb,wb))
    #pragma unroll
    for (int q = 0; q < 4; ++q) {
        if (4 * lg + q == lr) sq[16 * wa + lr] = acc_a[wa][q];
    }
    #pragma unroll
    for (int q = 0; q < 4; ++q) {
        if (4 * lg + q == lr) sq[16 * wb + lr] = acc_b[wb][q];
    }
    __syncthreads();

    const float lam = 0.06f * normal_cdf_f(l_raw[s]);
    const float one_m2l = 1.0f - 2.0f * lam;

    float llsum = 0.0f;
    #pragma unroll
    for (int TC = 0; TC < 8; ++TC) {
        if (TC >= wa) llsum += tile_ll(acc_a[TC], wa, TC, lg, lr, sq, csym, asym, lam, one_m2l);
        if (TC >= wb) llsum += tile_ll(acc_b[TC], wb, TC, lg, lr, sq, csym, asym, lam, one_m2l);
    }

    const float wtot = wave_sum(llsum);
    if (l == 0) wsum[w] = wtot;
    __syncthreads();
    if (t == 0) sums[s] = wsum[0] + wsum[1] + wsum[2] + wsum[3];
}

// ---------------------------------------------------------------------------
// Kernel 3: deterministic mean over S
// ---------------------------------------------------------------------------
__global__ __launch_bounds__(256) void reduce_kernel(
        const float* __restrict__ sums, float* __restrict__ out) {
    __shared__ double sh[256];
    const int t = threadIdx.x;
    double acc = 0.0;
    for (int i = t; i < S_TOT; i += 256) acc += (double)sums[i];
    sh[t] = acc;
    __syncthreads();
    for (int off = 128; off > 0; off >>= 1) {
        if (t < off) sh[t] += sh[t + off];
        __syncthreads();
    }
    if (t == 0) out[0] = (float)(sh[0] / (double)S_TOT);
}

// ---------------------------------------------------------------------------
extern "C" void kernel_launch(void* const* d_in, const int* in_sizes, int n_in,
                              void* d_out, int out_size, void* d_ws, size_t ws_size,
                              hipStream_t stream) {
    (void)in_sizes; (void)n_in; (void)out_size;
    const float* d_raw = (const float*)d_in[0];
    const float* c_raw = (const float*)d_in[1];
    const float* a_raw = (const float*)d_in[2];
    const float* l_raw = (const float*)d_in[3];
    const int*   all_t = (const int*)d_in[4];
    const int*   cor_t = (const int*)d_in[5];
    float* out = (float*)d_out;

    char*  ws   = (char*)d_ws;
    float* sums = (float*)ws;                               // 8 KB
    float* csym = (float*)(ws + 8192);                      // 64 KB
    float* asym = (float*)(ws + 8192 + 65536);              // 64 KB
    char*  xbase = ws + 8192 + 2 * 65536;
    const size_t per_sample = (size_t)NNODES * KPAD * 2 * 2; // hi+lo bf16 = 64 KB

    size_t head = 8192 + 2 * 65536;
    size_t avail = (ws_size > head) ? ws_size - head : 0;
    int chunk = (int)(avail / per_sample);
    if (chunk > S_TOT) chunk = S_TOT;
    if (chunk < 1) chunk = 1;

    prep_counts<<<64, 256, 0, stream>>>(all_t, cor_t, asym, csym);

    for (int s0 = 0; s0 < S_TOT; s0 += chunk) {
        const int nblk = (S_TOT - s0 < chunk) ? (S_TOT - s0) : chunk;
        ushort_t* xhi = (ushort_t*)xbase;
        ushort_t* xlo = (ushort_t*)(xbase + (size_t)chunk * (per_sample / 2));
        traj_kernel<<<nblk, 64, 0, stream>>>(d_raw, c_raw, a_raw, xhi, xlo, s0);
        ll_kernel<<<nblk, 256, 0, stream>>>(xhi, xlo, l_raw, csym, asym, sums, s0);
    }
    reduce_kernel<<<1, 256, 0, stream>>>(sums, out);
}

// Round 3
// 162.803 us; speedup vs baseline: 4.0607x; 2.0219x over previous
//
#include <hip/hip_runtime.h>
#include <math.h>

#define S_TOT   2048
#define NNODES  128
#define D_DIM   127
#define N_STEPS 126

typedef unsigned short ushort_t;
typedef unsigned int   uint_t;
typedef __attribute__((ext_vector_type(8))) short bfrag;   // 8 bf16 = 4 VGPR
typedef __attribute__((ext_vector_type(4))) float f4;

__device__ __forceinline__ float softplus_f(float x) {
    return log1pf(expf(-fabsf(x))) + fmaxf(x, 0.0f);
}
__device__ __forceinline__ float normal_cdf_f(float x) {
    return 0.5f * (1.0f + erff(x * 0.7071067811865475f));
}
__device__ __forceinline__ float frl(float x, int lane) {
    return __int_as_float(__builtin_amdgcn_readlane(__float_as_int(x), lane));
}
// 64-lane sum via DPP; returns wave-uniform total.
__device__ __forceinline__ float wave_sum(float x) {
    float r = x; int v;
    v = __builtin_amdgcn_update_dpp(0, __float_as_int(r), 0x111, 0xf, 0xf, true); r += __int_as_float(v);
    v = __builtin_amdgcn_update_dpp(0, __float_as_int(r), 0x112, 0xf, 0xf, true); r += __int_as_float(v);
    v = __builtin_amdgcn_update_dpp(0, __float_as_int(r), 0x114, 0xf, 0xf, true); r += __int_as_float(v);
    v = __builtin_amdgcn_update_dpp(0, __float_as_int(r), 0x118, 0xf, 0xf, true); r += __int_as_float(v);
    v = __builtin_amdgcn_update_dpp(0, __float_as_int(r), 0x142, 0xa, 0xf, true); r += __int_as_float(v);
    v = __builtin_amdgcn_update_dpp(0, __float_as_int(r), 0x143, 0xc, 0xf, true); r += __int_as_float(v);
    return frl(r, 63);
}
__device__ __forceinline__ ushort_t f2bf(float x) {        // RNE fp32 -> bf16
    uint_t u = __float_as_uint(x);
    uint_t r = u + 0x7fffu + ((u >> 16) & 1u);
    return (ushort_t)(r >> 16);
}
__device__ __forceinline__ float bf2f(ushort_t h) {
    return __uint_as_float(((uint_t)h) << 16);
}

// ---------------------------------------------------------------------------
// Kernel 0: symmetrized counts packed as bf16 pair: lo = csym, hi = asym-csym
// (integers <= 158: exact in bf16)
// ---------------------------------------------------------------------------
__global__ __launch_bounds__(256) void prep_counts(
        const int* __restrict__ all_t, const int* __restrict__ cor_t,
        uint_t* __restrict__ pk) {
    int i = blockIdx.x * 256 + threadIdx.x;       // 16384
    int n = i >> 7, m = i & 127;
    int at = all_t[i], ct = cor_t[i];
    if (n != m) { at += all_t[m * 128 + n]; ct += cor_t[m * 128 + n]; }
    uint_t lo = f2bf((float)ct);
    uint_t hi = f2bf((float)(at - ct));
    pk[i] = lo | (hi << 16);
}

// ---------------------------------------------------------------------------
// Kernel 1: trajectory. One wave per sample; lane l owns dims 2l, 2l+1.
// Emits x as bf16 hi/lo planes, [chunk][128 rows][64 uint words] (dim127 = 0).
// ---------------------------------------------------------------------------
__device__ __forceinline__ uint_t pack_pair(float x0, float x1, float& r0, float& r1) {
    ushort_t h0 = f2bf(x0), h1 = f2bf(x1);
    r0 = x0 - bf2f(h0); r1 = x1 - bf2f(h1);
    return (uint_t)h0 | ((uint_t)h1 << 16);
}

__global__ __launch_bounds__(64) void traj_kernel(
        const float* __restrict__ d_raw, const float* __restrict__ c_raw,
        const float* __restrict__ a_raw,
        uint_t* __restrict__ xhi, uint_t* __restrict__ xlo,
        int s_base) {
    const int li = blockIdx.x;
    const int s  = s_base + li;
    const int lane = threadIdx.x;
    const bool d1ok = lane < 63;                  // dim 2l+1 <= 126

    float dlo = softplus_f(d_raw[(size_t)s * D_DIM + lane]);
    float dhi = d1ok ? softplus_f(d_raw[(size_t)s * D_DIM + 64 + lane]) : 0.0f;
    float clo = c_raw[(size_t)s * N_STEPS + lane];
    float chi = (lane < 62) ? c_raw[(size_t)s * N_STEPS + 64 + lane] : 0.0f;

    float v0 = (lane == 0) ? 1.0f : 0.0f, v1 = 0.0f;
    float x0 = frl(dlo, 0) * v0, x1 = 0.0f;

    uint_t* hrow = xhi + (size_t)li * NNODES * 64;
    uint_t* lrow = xlo + (size_t)li * NNODES * 64;
    hrow[lane] = 0u; lrow[lane] = 0u;             // row 0 zeros
    hrow += 64; lrow += 64;
    {
        float r0, r1;
        hrow[lane] = pack_pair(x0, x1, r0, r1);
        float rr0, rr1;
        lrow[lane] = pack_pair(r0, r1, rr0, rr1);
    }

    const float* ap = a_raw + (size_t)s * N_STEPS * D_DIM;
#define LD_A(r, u, v) { const float* _p = ap + (size_t)(r) * D_DIM + 2 * lane; \
                        u = _p[0]; v = d1ok ? _p[1] : 0.0f; }
    float pa0, pb0, pa1, pb1, pa2, pb2, pa3, pb3;
    LD_A(0, pa0, pb0); LD_A(1, pa1, pb1); LD_A(2, pa2, pb2); LD_A(3, pa3, pb3);

    for (int i = 0; i < N_STEPS; ++i) {
        const float ca = pa0, cb = pb0;
        pa0 = pa1; pb0 = pb1; pa1 = pa2; pb1 = pb2; pa2 = pa3; pb2 = pb3;
        if (i + 4 < N_STEPS) LD_A(i + 4, pa3, pb3);

        float va = wave_sum(v0 * ca + v1 * cb);
        float aa = wave_sum(ca * ca + cb * cb);
        const float vE0 = frl(v0, 0), vE1 = frl(v1, 0);
        const float aE0 = frl(ca, 0), aE1 = frl(cb, 0);
        // LAPACK Householder sign (||v|| == 1 by construction)
        const float s_  = (vE0 >= 0.0f) ? 1.0f : -1.0f;
        const float ua  = aE0 + (va - vE0 * aE0) * __builtin_amdgcn_rcpf(vE0 + s_);
        const float w1  = aE1 - ua * vE1 * s_;
        const float sgn = (w1 >= 0.0f) ? -1.0f : 1.0f;
        const float inv = sgn * __builtin_amdgcn_rsqf(aa - va * va);

        const float ci = (i < 64) ? frl(clo, i) : frl(chi, i - 64);
        const float cosc = __cosf(ci), sinc = __sinf(ci), sf = sinc * inv;
        v0 = cosc * v0 + sf * (ca - va * v0);
        v1 = cosc * v1 + sf * (cb - va * v1);

        const int di = i + 1;
        const float dstep = (di < 64) ? frl(dlo, di) : frl(dhi, di - 64);
        x0 += dstep * v0;
        x1 += dstep * v1;

        hrow += 64; lrow += 64;
        float r0, r1;
        hrow[lane] = pack_pair(x0, x1, r0, r1);
        float rr0, rr1;
        lrow[lane] = pack_pair(r0, r1, rr0, rr1);
    }
#undef LD_A
}

// ---------------------------------------------------------------------------
// Kernel 2: MFMA gram (K split in two 32KB LDS halves) + B-S tail log-lik.
// 4 waves; wave w owns tile-rows {w, 7-w} via template<int W> (acc = 9 f4).
// ---------------------------------------------------------------------------
__device__ __forceinline__ bfrag ldfrag(const ushort_t* base, int row, int kelem) {
    int byte = ((row << 7) + (kelem << 1)) ^ ((row & 7) << 4);
    return *(const bfrag*)((const char*)base + byte);
}

__device__ __forceinline__ void fill_half(ushort_t* Hs, ushort_t* Ls,
        const uint_t* gh, const uint_t* gl, int kh, int t) {
    #pragma unroll
    for (int ii = 0; ii < 4; ++ii) {
        const int i = t + ii * 256;               // 1024 = 128 rows * 8 chunks
        const int row = i >> 3, j = i & 7;
        const uint4 vh = *(const uint4*)(gh + row * 64 + kh * 32 + j * 4);
        const uint4 vl = *(const uint4*)(gl + row * 64 + kh * 32 + j * 4);
        const int b = ((row << 7) + (j << 4)) ^ ((row & 7) << 4);
        *(uint4*)((char*)Hs + b) = vh;
        *(uint4*)((char*)Ls + b) = vl;
    }
}

template<int W>
__device__ __forceinline__ void gram_half(const ushort_t* Hs, const ushort_t* Ls,
                                          f4 (&acc)[9], int lr, int lg) {
    constexpr int RA = W, RB = 7 - W;
    #pragma unroll
    for (int ks = 0; ks < 2; ++ks) {
        const int kb = ks * 32 + lg * 8;
        const bfrag ha = ldfrag(Hs, RA * 16 + lr, kb), la = ldfrag(Ls, RA * 16 + lr, kb);
        const bfrag hb = ldfrag(Hs, RB * 16 + lr, kb), lb = ldfrag(Ls, RB * 16 + lr, kb);
        #pragma unroll
        for (int TC = W; TC < 8; ++TC) {
            const bfrag bh = ldfrag(Hs, TC * 16 + lr, kb), bl = ldfrag(Ls, TC * 16 + lr, kb);
            {
                f4& a = acc[TC - W];
                a = __builtin_amdgcn_mfma_f32_16x16x32_bf16(ha, bh, a, 0, 0, 0);
                a = __builtin_amdgcn_mfma_f32_16x16x32_bf16(ha, bl, a, 0, 0, 0);
                a = __builtin_amdgcn_mfma_f32_16x16x32_bf16(la, bh, a, 0, 0, 0);
            }
            if (TC >= RB) {
                f4& a = acc[TC + 1];
                a = __builtin_amdgcn_mfma_f32_16x16x32_bf16(hb, bh, a, 0, 0, 0);
                a = __builtin_amdgcn_mfma_f32_16x16x32_bf16(hb, bl, a, 0, 0, 0);
                a = __builtin_amdgcn_mfma_f32_16x16x32_bf16(lb, bh, a, 0, 0, 0);
            }
        }
    }
}

template<int W>
__device__ __forceinline__ void write_sq(const f4 (&acc)[9], float* sq, int lr, int lg) {
    #pragma unroll
    for (int q = 0; q < 4; ++q) {
        if (4 * lg + q == lr) {
            sq[W * 16 + lr]       = acc[0][q];       // tile (W,W)
            sq[(7 - W) * 16 + lr] = acc[8 - W][q];   // tile (7-W,7-W)
        }
    }
}

// Borjesson-Sundberg Q(z) ~ phi(z)/((1-A)z + A*sqrt(z^2+B)); rel err <~0.5%.
// q_axb = F1 + F2 - 2 F1 F2 is relative-accurate (no cancellation).
__device__ __forceinline__ float entry_ll(float g, float sqn, float sqm,
        uint_t cw, float lam, float one_m2l) {
    const float d2 = fmaxf(sqn + sqm - 2.0f * g, 0.0f);
    const float pd = __builtin_amdgcn_sqrtf(d2);
    const float A = 0.344f, B = 5.334f, IA = 0.656f, C = 0.3989422804f;
    const float z1 = 0.70710678f * pd, z2 = 0.5f * pd;
    const float e1 = __expf(-0.25f  * d2) * C;   // phi(z1)
    const float e2 = __expf(-0.125f * d2) * C;   // phi(z2)
    const float den1 = fmaf(A, __builtin_amdgcn_sqrtf(fmaf(0.5f,  d2, B)), IA * z1);
    const float den2 = fmaf(A, __builtin_amdgcn_sqrtf(fmaf(0.25f, d2, B)), IA * z2);
    const float F1 = e1 * __builtin_amdgcn_rcpf(den1);
    const float F2 = e2 * __builtin_amdgcn_rcpf(den2);
    const float qax = F1 + F2 - 2.0f * F1 * F2;
    float qp = fmaf(one_m2l, qax, lam);
    qp = fminf(fmaxf(qp, 1e-7f), 1.0f - 1e-7f);
    const float pp = 1.0f - qp;
    const float c   = bf2f((ushort_t)(cw & 0xffffu));
    const float amc = bf2f((ushort_t)(cw >> 16));
    return c * __logf(pp) + amc * __logf(qp);
}

__device__ __forceinline__ float tile_ll(f4 a, int TR, int TC, bool diag,
        int lr, int lg, const float* sq, const uint_t* __restrict__ cnt,
        float lam, float one_m2l) {
    float s = 0.0f;
    #pragma unroll
    for (int q = 0; q < 4; ++q) {
        const int n = TR * 16 + 4 * lg + q;
        const int m = TC * 16 + lr;
        if (!diag || (4 * lg + q) <= lr)
            s += entry_ll(a[q], sq[n], sq[m], cnt[n * 128 + m], lam, one_m2l);
    }
    return s;
}

template<int W>
__device__ __forceinline__ float epi(const f4 (&acc)[9], const float* sq,
        const uint_t* __restrict__ cnt, int lr, int lg, float lam, float one_m2l) {
    constexpr int RA = W, RB = 7 - W;
    float s = 0.0f;
    #pragma unroll
    for (int TC = W; TC < 8; ++TC) {
        s += tile_ll(acc[TC - W], RA, TC, (TC == RA), lr, lg, sq, cnt, lam, one_m2l);
        if (TC >= RB)
            s += tile_ll(acc[TC + 1], RB, TC, (TC == RB), lr, lg, sq, cnt, lam, one_m2l);
    }
    return s;
}

__global__ __launch_bounds__(256, 3) void ll_kernel(
        const uint_t* __restrict__ xhi_g, const uint_t* __restrict__ xlo_g,
        const float* __restrict__ l_raw, const uint_t* __restrict__ cnt,
        float* __restrict__ sums, int s_base) {
    const int li = blockIdx.x;
    const int s  = s_base + li;
    const int t  = threadIdx.x;

    __shared__ __align__(16) ushort_t Hs[NNODES * 64];
    __shared__ __align__(16) ushort_t Ls[NNODES * 64];
    __shared__ float sq[NNODES];
    __shared__ float wsum[4];

    const uint_t* gh = xhi_g + (size_t)li * NNODES * 64;
    const uint_t* gl = xlo_g + (size_t)li * NNODES * 64;
    const int l = t & 63, w = t >> 6, lr = l & 15, lg = l >> 4;

    f4 acc[9];
    #pragma unroll
    for (int i = 0; i < 9; ++i) acc[i] = (f4)(0.0f);

    fill_half(Hs, Ls, gh, gl, 0, t);
    __syncthreads();
    switch (w) {
        case 0: gram_half<0>(Hs, Ls, acc, lr, lg); break;
        case 1: gram_half<1>(Hs, Ls, acc, lr, lg); break;
        case 2: gram_half<2>(Hs, Ls, acc, lr, lg); break;
        default: gram_half<3>(Hs, Ls, acc, lr, lg); break;
    }
    __syncthreads();
    fill_half(Hs, Ls, gh, gl, 1, t);
    __syncthreads();
    switch (w) {
        case 0: gram_half<0>(Hs, Ls, acc, lr, lg); break;
        case 1: gram_half<1>(Hs, Ls, acc, lr, lg); break;
        case 2: gram_half<2>(Hs, Ls, acc, lr, lg); break;
        default: gram_half<3>(Hs, Ls, acc, lr, lg); break;
    }
    switch (w) {
        case 0: write_sq<0>(acc, sq, lr, lg); break;
        case 1: write_sq<1>(acc, sq, lr, lg); break;
        case 2: write_sq<2>(acc, sq, lr, lg); break;
        default: write_sq<3>(acc, sq, lr, lg); break;
    }
    __syncthreads();

    const float lam = 0.06f * normal_cdf_f(l_raw[s]);
    const float one_m2l = 1.0f - 2.0f * lam;
    float ll = 0.0f;
    switch (w) {
        case 0: ll = epi<0>(acc, sq, cnt, lr, lg, lam, one_m2l); break;
        case 1: ll = epi<1>(acc, sq, cnt, lr, lg, lam, one_m2l); break;
        case 2: ll = epi<2>(acc, sq, cnt, lr, lg, lam, one_m2l); break;
        default: ll = epi<3>(acc, sq, cnt, lr, lg, lam, one_m2l); break;
    }

    const float wtot = wave_sum(ll);
    if (l == 0) wsum[w] = wtot;
    __syncthreads();
    if (t == 0) sums[s] = wsum[0] + wsum[1] + wsum[2] + wsum[3];
}

// ---------------------------------------------------------------------------
// Kernel 3: deterministic mean over S
// ---------------------------------------------------------------------------
__global__ __launch_bounds__(256) void reduce_kernel(
        const float* __restrict__ sums, float* __restrict__ out) {
    __shared__ double sh[256];
    const int t = threadIdx.x;
    double acc = 0.0;
    for (int i = t; i < S_TOT; i += 256) acc += (double)sums[i];
    sh[t] = acc;
    __syncthreads();
    for (int off = 128; off > 0; off >>= 1) {
        if (t < off) sh[t] += sh[t + off];
        __syncthreads();
    }
    if (t == 0) out[0] = (float)(sh[0] / (double)S_TOT);
}

// ---------------------------------------------------------------------------
extern "C" void kernel_launch(void* const* d_in, const int* in_sizes, int n_in,
                              void* d_out, int out_size, void* d_ws, size_t ws_size,
                              hipStream_t stream) {
    (void)in_sizes; (void)n_in; (void)out_size;
    const float* d_raw = (const float*)d_in[0];
    const float* c_raw = (const float*)d_in[1];
    const float* a_raw = (const float*)d_in[2];
    const float* l_raw = (const float*)d_in[3];
    const int*   all_t = (const int*)d_in[4];
    const int*   cor_t = (const int*)d_in[5];
    float* out = (float*)d_out;

    char*   ws   = (char*)d_ws;
    float*  sums = (float*)ws;                        // 8 KB
    uint_t* cnt  = (uint_t*)(ws + 8192);              // 64 KB packed counts
    char*   xbase = ws + 8192 + 65536;
    const size_t plane_per = (size_t)NNODES * 64 * sizeof(uint_t);  // 32 KB
    const size_t per_sample = 2 * plane_per;                        // 64 KB

    const size_t head = 8192 + 65536;
    size_t avail = (ws_size > head) ? ws_size - head : 0;
    int chunk = (int)(avail / per_sample);
    if (chunk > S_TOT) chunk = S_TOT;
    if (chunk < 1) chunk = 1;

    prep_counts<<<64, 256, 0, stream>>>(all_t, cor_t, cnt);

    for (int s0 = 0; s0 < S_TOT; s0 += chunk) {
        const int nblk = (S_TOT - s0 < chunk) ? (S_TOT - s0) : chunk;
        uint_t* xhi = (uint_t*)xbase;
        uint_t* xlo = (uint_t*)(xbase + (size_t)chunk * plane_per);
        traj_kernel<<<nblk, 64, 0, stream>>>(d_raw, c_raw, a_raw, xhi, xlo, s0);
        ll_kernel<<<nblk, 256, 0, stream>>>(xhi, xlo, l_raw, cnt, sums, s0);
    }
    reduce_kernel<<<1, 256, 0, stream>>>(sums, out);
}

// Round 4
// 126.574 us; speedup vs baseline: 5.2230x; 1.2862x over previous
//
#include <hip/hip_runtime.h>
#include <math.h>

#define S_TOT   2048
#define NNODES  128
#define D_DIM   127
#define N_STEPS 126

typedef unsigned short ushort_t;
typedef unsigned int   uint_t;
typedef __attribute__((ext_vector_type(8))) short bfrag;   // 8 bf16 = 4 VGPR
typedef __attribute__((ext_vector_type(4))) float f4;

__device__ __forceinline__ float softplus_f(float x) {
    return log1pf(expf(-fabsf(x))) + fmaxf(x, 0.0f);
}
__device__ __forceinline__ float normal_cdf_f(float x) {
    return 0.5f * (1.0f + erff(x * 0.7071067811865475f));
}
__device__ __forceinline__ float frl(float x, int lane) {
    return __int_as_float(__builtin_amdgcn_readlane(__float_as_int(x), lane));
}
// 64-lane sum via DPP; returns wave-uniform total.
__device__ __forceinline__ float wave_sum(float x) {
    float r = x; int v;
    v = __builtin_amdgcn_update_dpp(0, __float_as_int(r), 0x111, 0xf, 0xf, true); r += __int_as_float(v);
    v = __builtin_amdgcn_update_dpp(0, __float_as_int(r), 0x112, 0xf, 0xf, true); r += __int_as_float(v);
    v = __builtin_amdgcn_update_dpp(0, __float_as_int(r), 0x114, 0xf, 0xf, true); r += __int_as_float(v);
    v = __builtin_amdgcn_update_dpp(0, __float_as_int(r), 0x118, 0xf, 0xf, true); r += __int_as_float(v);
    v = __builtin_amdgcn_update_dpp(0, __float_as_int(r), 0x142, 0xa, 0xf, true); r += __int_as_float(v);
    v = __builtin_amdgcn_update_dpp(0, __float_as_int(r), 0x143, 0xc, 0xf, true); r += __int_as_float(v);
    return frl(r, 63);
}
__device__ __forceinline__ ushort_t f2bf(float x) {        // RNE fp32 -> bf16
    uint_t u = __float_as_uint(x);
    uint_t r = u + 0x7fffu + ((u >> 16) & 1u);
    return (ushort_t)(r >> 16);
}
__device__ __forceinline__ float bf2f(ushort_t h) {
    return __uint_as_float(((uint_t)h) << 16);
}
__device__ __forceinline__ uint_t pack2(float x0, float x1) {
    return (uint_t)f2bf(x0) | ((uint_t)f2bf(x1) << 16);
}

// ---------------------------------------------------------------------------
// Kernel 0: symmetrized counts packed as bf16 pair: lo = csym, hi = asym-csym
// ---------------------------------------------------------------------------
__global__ __launch_bounds__(256) void prep_counts(
        const int* __restrict__ all_t, const int* __restrict__ cor_t,
        uint_t* __restrict__ pk) {
    int i = blockIdx.x * 256 + threadIdx.x;       // 16384
    int n = i >> 7, m = i & 127;
    int at = all_t[i], ct = cor_t[i];
    if (n != m) { at += all_t[m * 128 + n]; ct += cor_t[m * 128 + n]; }
    pk[i] = (uint_t)f2bf((float)ct) | ((uint_t)f2bf((float)(at - ct)) << 16);
}

// ---------------------------------------------------------------------------
// Kernel 1: trajectory. One wave per sample; lane l owns dims 2l, 2l+1.
// Emits x as bf16, [chunk][128 rows][64 dwords] (dim 127 = 0).
// __launch_bounds__(64, 1): min 1 wave/EU -> full 512-VGPR budget (we are
// grid-limited to 2 waves/SIMD; round-3 build got VGPR=16 and spilled).
// ---------------------------------------------------------------------------
__global__ __launch_bounds__(64, 1) void traj_kernel(
        const float* __restrict__ d_raw, const float* __restrict__ c_raw,
        const float* __restrict__ a_raw,
        uint_t* __restrict__ xout, int s_base) {
    const int li = blockIdx.x;
    const int s  = s_base + li;
    const int lane = threadIdx.x;
    const bool d1ok = lane < 63;                  // dim 2l+1 <= 126

    float dlo = softplus_f(d_raw[(size_t)s * D_DIM + lane]);
    float dhi = d1ok ? softplus_f(d_raw[(size_t)s * D_DIM + 64 + lane]) : 0.0f;
    float clo = c_raw[(size_t)s * N_STEPS + lane];
    float chi = (lane < 62) ? c_raw[(size_t)s * N_STEPS + 64 + lane] : 0.0f;

    float v0 = (lane == 0) ? 1.0f : 0.0f, v1 = 0.0f;
    float x0 = frl(dlo, 0) * v0, x1 = 0.0f;

    uint_t* hrow = xout + (size_t)li * NNODES * 64;
    hrow[lane] = 0u;                              // row 0 zeros
    hrow += 64;
    hrow[lane] = pack2(x0, x1);

    const float* ap = a_raw + (size_t)s * N_STEPS * D_DIM;
#define LD_A(r, u, v) { const float* _p = ap + (size_t)(r) * D_DIM + 2 * lane; \
                        u = _p[0]; v = d1ok ? _p[1] : 0.0f; }
    float pa0, pb0, pa1, pb1, pa2, pb2, pa3, pb3;
    LD_A(0, pa0, pb0); LD_A(1, pa1, pb1); LD_A(2, pa2, pb2); LD_A(3, pa3, pb3);

    for (int i = 0; i < N_STEPS; ++i) {
        const float ca = pa0, cb = pb0;
        pa0 = pa1; pb0 = pb1; pa1 = pa2; pb1 = pb2; pa2 = pa3; pb2 = pb3;
        if (i + 4 < N_STEPS) LD_A(i + 4, pa3, pb3);

        float va = wave_sum(v0 * ca + v1 * cb);
        float aa = wave_sum(ca * ca + cb * cb);
        const float vE0 = frl(v0, 0), vE1 = frl(v1, 0);
        const float aE0 = frl(ca, 0), aE1 = frl(cb, 0);
        // LAPACK Householder sign (||v|| == 1 by construction)
        const float s_  = (vE0 >= 0.0f) ? 1.0f : -1.0f;
        const float ua  = aE0 + (va - vE0 * aE0) * __builtin_amdgcn_rcpf(vE0 + s_);
        const float w1  = aE1 - ua * vE1 * s_;
        const float sgn = (w1 >= 0.0f) ? -1.0f : 1.0f;
        const float inv = sgn * __builtin_amdgcn_rsqf(aa - va * va);

        const float ci = (i < 64) ? frl(clo, i) : frl(chi, i - 64);
        const float cosc = __cosf(ci), sinc = __sinf(ci), sf = sinc * inv;
        v0 = cosc * v0 + sf * (ca - va * v0);
        v1 = cosc * v1 + sf * (cb - va * v1);

        const int di = i + 1;
        const float dstep = (di < 64) ? frl(dlo, di) : frl(dhi, di - 64);
        x0 += dstep * v0;
        x1 += dstep * v1;

        hrow += 64;
        hrow[lane] = pack2(x0, x1);
    }
#undef LD_A
}

// ---------------------------------------------------------------------------
// Kernel 2: MFMA gram (single 32KB bf16 LDS stage) + B-S tail log-lik.
// 4 waves; wave w owns tile-rows {w, 7-w} via template<int W> (acc = 9 f4).
// ---------------------------------------------------------------------------
__device__ __forceinline__ bfrag ldfrag(const ushort_t* base, int row, int kelem) {
    int byte = ((row << 8) + (kelem << 1)) ^ ((row & 7) << 4);
    return *(const bfrag*)((const char*)base + byte);
}

template<int W>
__device__ __forceinline__ void gram_w(const ushort_t* Xs, f4 (&acc)[9],
                                       int lr, int lg) {
    constexpr int RA = W, RB = 7 - W;
    #pragma unroll
    for (int ks = 0; ks < 4; ++ks) {
        const int kb = ks * 32 + lg * 8;
        const bfrag ha = ldfrag(Xs, RA * 16 + lr, kb);
        const bfrag hb = ldfrag(Xs, RB * 16 + lr, kb);
        #pragma unroll
        for (int TC = W; TC < 8; ++TC) {
            const bfrag bh = ldfrag(Xs, TC * 16 + lr, kb);
            acc[TC - W] = __builtin_amdgcn_mfma_f32_16x16x32_bf16(ha, bh, acc[TC - W], 0, 0, 0);
            if (TC >= RB)
                acc[TC + 1] = __builtin_amdgcn_mfma_f32_16x16x32_bf16(hb, bh, acc[TC + 1], 0, 0, 0);
        }
    }
}

template<int W>
__device__ __forceinline__ void write_sq(const f4 (&acc)[9], float* sq, int lr, int lg) {
    #pragma unroll
    for (int q = 0; q < 4; ++q) {
        if (4 * lg + q == lr) {
            sq[W * 16 + lr]       = acc[0][q];       // tile (W,W)
            sq[(7 - W) * 16 + lr] = acc[8 - W][q];   // tile (7-W,7-W)
        }
    }
}

// Borjesson-Sundberg Q(z) ~ phi(z)/((1-A)z + A*sqrt(z^2+B)); rel err <~0.5%.
// q_axb = F1 + F2 - 2 F1 F2 is relative-accurate (no cancellation).
__device__ __forceinline__ float entry_ll(float g, float sqn, float sqm,
        uint_t cw, float lam, float one_m2l) {
    const float d2 = fmaxf(sqn + sqm - 2.0f * g, 0.0f);
    const float pd = __builtin_amdgcn_sqrtf(d2);
    const float A = 0.344f, B = 5.334f, IA = 0.656f, C = 0.3989422804f;
    const float z1 = 0.70710678f * pd, z2 = 0.5f * pd;
    const float e1 = __expf(-0.25f  * d2) * C;   // phi(z1)
    const float e2 = __expf(-0.125f * d2) * C;   // phi(z2)
    const float den1 = fmaf(A, __builtin_amdgcn_sqrtf(fmaf(0.5f,  d2, B)), IA * z1);
    const float den2 = fmaf(A, __builtin_amdgcn_sqrtf(fmaf(0.25f, d2, B)), IA * z2);
    const float F1 = e1 * __builtin_amdgcn_rcpf(den1);
    const float F2 = e2 * __builtin_amdgcn_rcpf(den2);
    const float qax = F1 + F2 - 2.0f * F1 * F2;
    float qp = fmaf(one_m2l, qax, lam);
    qp = fminf(fmaxf(qp, 1e-7f), 1.0f - 1e-7f);
    const float pp = 1.0f - qp;
    const float c   = bf2f((ushort_t)(cw & 0xffffu));
    const float amc = bf2f((ushort_t)(cw >> 16));
    return c * __logf(pp) + amc * __logf(qp);
}

__device__ __forceinline__ float tile_ll(f4 a, int TR, int TC, bool diag,
        int lr, int lg, const float* sq, const uint_t* __restrict__ cnt,
        float lam, float one_m2l) {
    float s = 0.0f;
    #pragma unroll
    for (int q = 0; q < 4; ++q) {
        const int n = TR * 16 + 4 * lg + q;
        const int m = TC * 16 + lr;
        if (!diag || (4 * lg + q) <= lr)
            s += entry_ll(a[q], sq[n], sq[m], cnt[n * 128 + m], lam, one_m2l);
    }
    return s;
}

template<int W>
__device__ __forceinline__ float epi(const f4 (&acc)[9], const float* sq,
        const uint_t* __restrict__ cnt, int lr, int lg, float lam, float one_m2l) {
    constexpr int RA = W, RB = 7 - W;
    float s = 0.0f;
    #pragma unroll
    for (int TC = W; TC < 8; ++TC) {
        s += tile_ll(acc[TC - W], RA, TC, (TC == RA), lr, lg, sq, cnt, lam, one_m2l);
        if (TC >= RB)
            s += tile_ll(acc[TC + 1], RB, TC, (TC == RB), lr, lg, sq, cnt, lam, one_m2l);
    }
    return s;
}

__global__ __launch_bounds__(256, 4) void ll_kernel(
        const uint_t* __restrict__ x_g,
        const float* __restrict__ l_raw, const uint_t* __restrict__ cnt,
        float* __restrict__ sums, int s_base) {
    const int li = blockIdx.x;
    const int s  = s_base + li;
    const int t  = threadIdx.x;

    __shared__ __align__(16) ushort_t Xs[NNODES * 128];   // 32 KB
    __shared__ float sq[NNODES];
    __shared__ float wsum[4];

    const uint_t* gx = x_g + (size_t)li * NNODES * 64;
    const int l = t & 63, w = t >> 6, lr = l & 15, lg = l >> 4;

    // fill LDS (swizzled) with 16B chunks; 2048 chunks over 256 threads
    #pragma unroll
    for (int ii = 0; ii < 8; ++ii) {
        const int i = t + ii * 256;
        const int row = i >> 4, j = i & 15;
        const uint4 v = *(const uint4*)(gx + row * 64 + j * 4);
        const int b = ((row << 8) + (j << 4)) ^ ((row & 7) << 4);
        *(uint4*)((char*)Xs + b) = v;
    }
    __syncthreads();

    f4 acc[9];
    #pragma unroll
    for (int i = 0; i < 9; ++i) acc[i] = (f4)(0.0f);

    switch (w) {
        case 0: gram_w<0>(Xs, acc, lr, lg); write_sq<0>(acc, sq, lr, lg); break;
        case 1: gram_w<1>(Xs, acc, lr, lg); write_sq<1>(acc, sq, lr, lg); break;
        case 2: gram_w<2>(Xs, acc, lr, lg); write_sq<2>(acc, sq, lr, lg); break;
        default: gram_w<3>(Xs, acc, lr, lg); write_sq<3>(acc, sq, lr, lg); break;
    }
    __syncthreads();

    const float lam = 0.06f * normal_cdf_f(l_raw[s]);
    const float one_m2l = 1.0f - 2.0f * lam;
    float ll = 0.0f;
    switch (w) {
        case 0: ll = epi<0>(acc, sq, cnt, lr, lg, lam, one_m2l); break;
        case 1: ll = epi<1>(acc, sq, cnt, lr, lg, lam, one_m2l); break;
        case 2: ll = epi<2>(acc, sq, cnt, lr, lg, lam, one_m2l); break;
        default: ll = epi<3>(acc, sq, cnt, lr, lg, lam, one_m2l); break;
    }

    const float wtot = wave_sum(ll);
    if (l == 0) wsum[w] = wtot;
    __syncthreads();
    if (t == 0) sums[s] = wsum[0] + wsum[1] + wsum[2] + wsum[3];
}

// ---------------------------------------------------------------------------
// Kernel 3: deterministic mean over S
// ---------------------------------------------------------------------------
__global__ __launch_bounds__(256) void reduce_kernel(
        const float* __restrict__ sums, float* __restrict__ out) {
    __shared__ double sh[256];
    const int t = threadIdx.x;
    double acc = 0.0;
    for (int i = t; i < S_TOT; i += 256) acc += (double)sums[i];
    sh[t] = acc;
    __syncthreads();
    for (int off = 128; off > 0; off >>= 1) {
        if (t < off) sh[t] += sh[t + off];
        __syncthreads();
    }
    if (t == 0) out[0] = (float)(sh[0] / (double)S_TOT);
}

// ---------------------------------------------------------------------------
extern "C" void kernel_launch(void* const* d_in, const int* in_sizes, int n_in,
                              void* d_out, int out_size, void* d_ws, size_t ws_size,
                              hipStream_t stream) {
    (void)in_sizes; (void)n_in; (void)out_size;
    const float* d_raw = (const float*)d_in[0];
    const float* c_raw = (const float*)d_in[1];
    const float* a_raw = (const float*)d_in[2];
    const float* l_raw = (const float*)d_in[3];
    const int*   all_t = (const int*)d_in[4];
    const int*   cor_t = (const int*)d_in[5];
    float* out = (float*)d_out;

    char*   ws   = (char*)d_ws;
    float*  sums = (float*)ws;                        // 8 KB
    uint_t* cnt  = (uint_t*)(ws + 8192);              // 64 KB packed counts
    char*   xbase = ws + 8192 + 65536;
    const size_t per_sample = (size_t)NNODES * 64 * sizeof(uint_t);  // 32 KB

    const size_t head = 8192 + 65536;
    size_t avail = (ws_size > head) ? ws_size - head : 0;
    int chunk = (int)(avail / per_sample);
    if (chunk > S_TOT) chunk = S_TOT;
    if (chunk < 1) chunk = 1;

    prep_counts<<<64, 256, 0, stream>>>(all_t, cor_t, cnt);

    for (int s0 = 0; s0 < S_TOT; s0 += chunk) {
        const int nblk = (S_TOT - s0 < chunk) ? (S_TOT - s0) : chunk;
        uint_t* xbuf = (uint_t*)xbase;
        traj_kernel<<<nblk, 64, 0, stream>>>(d_raw, c_raw, a_raw, xbuf, s0);
        ll_kernel<<<nblk, 256, 0, stream>>>(xbuf, l_raw, cnt, sums, s0);
    }
    reduce_kernel<<<1, 256, 0, stream>>>(sums, out);
}

// Round 5
// 114.949 us; speedup vs baseline: 5.7512x; 1.1011x over previous
//
#include <hip/hip_runtime.h>
#include <math.h>

#define S_TOT   2048
#define NNODES  128
#define D_DIM   127
#define N_STEPS 126

typedef unsigned short ushort_t;
typedef unsigned int   uint_t;
typedef __attribute__((ext_vector_type(8))) short bfrag;   // 8 bf16 = 4 VGPR
typedef __attribute__((ext_vector_type(4))) float f4;

__device__ __forceinline__ float softplus_f(float x) {
    return log1pf(expf(-fabsf(x))) + fmaxf(x, 0.0f);
}
__device__ __forceinline__ float normal_cdf_f(float x) {
    return 0.5f * (1.0f + erff(x * 0.7071067811865475f));
}
__device__ __forceinline__ float frl(float x, int lane) {
    return __int_as_float(__builtin_amdgcn_readlane(__float_as_int(x), lane));
}
// 64-lane sum via DPP; returns wave-uniform total.
__device__ __forceinline__ float wave_sum(float x) {
    float r = x; int v;
    v = __builtin_amdgcn_update_dpp(0, __float_as_int(r), 0x111, 0xf, 0xf, true); r += __int_as_float(v);
    v = __builtin_amdgcn_update_dpp(0, __float_as_int(r), 0x112, 0xf, 0xf, true); r += __int_as_float(v);
    v = __builtin_amdgcn_update_dpp(0, __float_as_int(r), 0x114, 0xf, 0xf, true); r += __int_as_float(v);
    v = __builtin_amdgcn_update_dpp(0, __float_as_int(r), 0x118, 0xf, 0xf, true); r += __int_as_float(v);
    v = __builtin_amdgcn_update_dpp(0, __float_as_int(r), 0x142, 0xa, 0xf, true); r += __int_as_float(v);
    v = __builtin_amdgcn_update_dpp(0, __float_as_int(r), 0x143, 0xc, 0xf, true); r += __int_as_float(v);
    return frl(r, 63);
}
__device__ __forceinline__ ushort_t f2bf(float x) {        // RNE fp32 -> bf16
    uint_t u = __float_as_uint(x);
    uint_t r = u + 0x7fffu + ((u >> 16) & 1u);
    return (ushort_t)(r >> 16);
}
__device__ __forceinline__ float bf2f(ushort_t h) {
    return __uint_as_float(((uint_t)h) << 16);
}
// async global->LDS: each lane contributes 4B from its own global address;
// LDS dest = wave-uniform base + lane*4.
__device__ __forceinline__ void load_lds4(const void* g, void* l) {
    __builtin_amdgcn_global_load_lds(
        (const __attribute__((address_space(1))) unsigned int*)g,
        (__attribute__((address_space(3))) unsigned int*)l, 4, 0, 0);
}

// ---------------------------------------------------------------------------
// Kernel 0: symmetrized counts packed as bf16 pair: lo = csym, hi = asym-csym
// ---------------------------------------------------------------------------
__global__ __launch_bounds__(256) void prep_counts(
        const int* __restrict__ all_t, const int* __restrict__ cor_t,
        uint_t* __restrict__ pk) {
    int i = blockIdx.x * 256 + threadIdx.x;       // 16384
    int n = i >> 7, m = i & 127;
    int at = all_t[i], ct = cor_t[i];
    if (n != m) { at += all_t[m * 128 + n]; ct += cor_t[m * 128 + n]; }
    pk[i] = (uint_t)f2bf((float)ct) | ((uint_t)f2bf((float)(at - ct)) << 16);
}

// ---------------------------------------------------------------------------
// Kernel 1: trajectory. One wave per sample; lane l owns dims 2l, 2l+1.
// a-rows stream through a 16-slot LDS ring via global_load_lds, prefetch
// distance 8, counted vmcnt waits (3 vmem ops/iter: 1 store + 2 loads).
// ---------------------------------------------------------------------------
__global__ __launch_bounds__(64, 1) void traj_kernel(
        const float* __restrict__ d_raw, const float* __restrict__ c_raw,
        const float* __restrict__ a_raw,
        uint_t* __restrict__ xout, int s_base) {
    const int li = blockIdx.x;
    const int s  = s_base + li;
    const int lane = threadIdx.x;
    const bool d1ok = lane < 63;                  // dim 2l+1 <= 126

    __shared__ __align__(16) float ring[16 * 128 + 256];  // 8KB ring + d + c
    float* dls = &ring[2048];
    float* cls = &ring[2048 + 128];

    // d (softplus'd) and c into LDS for uniform broadcast reads
    float t0 = softplus_f(d_raw[(size_t)s * D_DIM + lane]);
    dls[lane] = t0;
    if (lane < 63) dls[64 + lane] = softplus_f(d_raw[(size_t)s * D_DIM + 64 + lane]);
    cls[lane] = c_raw[(size_t)s * N_STEPS + lane];
    if (lane < 62) cls[64 + lane] = c_raw[(size_t)s * N_STEPS + 64 + lane];

    const char* ag = (const char*)(a_raw + (size_t)s * N_STEPS * D_DIM);
    // ring prologue: rows 0..7 (rows are 508B; two 256B chunks, 2nd overlaps
    // by 4B only for row 125 -- not here)
    #pragma unroll
    for (int r = 0; r < 8; ++r) {
        const char* g = ag + r * 508;
        char* slot = (char*)&ring[r * 128];
        load_lds4(g + 4 * lane, slot);
        load_lds4(g + 256 + 4 * lane, slot + 256);
    }
    asm volatile("s_waitcnt vmcnt(0)" ::: "memory");

    // init state
    float v0 = (lane == 0) ? 1.0f : 0.0f, v1 = 0.0f;
    float x0 = (lane == 0) ? t0 : 0.0f, x1 = 0.0f;

    uint_t* xrow = xout + (size_t)li * NNODES * 64;
    xrow[lane] = 0u;                              // row 0
    xrow += 64;
    {
        uint_t pk; asm("v_cvt_pk_bf16_f32 %0, %1, %2" : "=v"(pk) : "v"(x0), "v"(x1));
        xrow[lane] = pk;                          // row 1
    }

    // "next" state for iter 0 (row 0)
    float car, cbm;
    {
        float2 nx = *(float2*)&ring[0 * 128 + 2 * lane];
        car = nx.x; cbm = d1ok ? nx.y : 0.0f;
    }
    float aa_n  = wave_sum(fmaf(car, car, cbm * cbm));
    float aE0n  = frl(car, 0), aE1n = frl(cbm, 0);
    float ci_n  = cls[0];
    float cosc_n = __cosf(ci_n), sinc_n = __sinf(ci_n);
    float dstep_n = dls[1];
    // v-pivot precompute (v = e0): vE0=1, s=1
    float vE0 = frl(v0, 0);
    float vE1s, rcp_v;
    {
        float ns = copysignf(1.0f, vE0);
        rcp_v = __builtin_amdgcn_rcpf(vE0 + ns);
        vE1s  = frl(v1, 0) * ns;
    }

#define STEP(i, DO_WAIT, DO_PF)                                               \
    {                                                                         \
        const float ca = car, cb = cbm, aa = aa_n;                            \
        const float aE0 = aE0n, aE1 = aE1n;                                   \
        const float cosc = cosc_n, sinc = sinc_n, dstep = dstep_n;            \
        if (DO_WAIT) asm volatile("s_waitcnt vmcnt(18)" ::: "memory");        \
        float2 nx = *(float2*)&ring[(((i) + 1) & 15) * 128 + 2 * lane];       \
        car = nx.x; cbm = d1ok ? nx.y : 0.0f;                                 \
        ci_n = cls[(i) + 1]; dstep_n = dls[(i) + 2];                          \
        aa_n = wave_sum(fmaf(car, car, cbm * cbm));                           \
        aE0n = frl(car, 0); aE1n = frl(cbm, 0);                               \
        cosc_n = __cosf(ci_n); sinc_n = __sinf(ci_n);                         \
        /* critical chain */                                                  \
        float va = wave_sum(fmaf(v0, ca, v1 * cb));                           \
        float ua = fmaf(fmaf(-vE0, aE0, va), rcp_v, aE0);                     \
        float w1 = fmaf(-ua, vE1s, aE1);                                      \
        float inv = __builtin_amdgcn_rsqf(fmaf(-va, va, aa));                 \
        float invs = (w1 >= 0.0f) ? -inv : inv;                               \
        float sf = sinc * invs;                                               \
        float tt0 = fmaf(-va, v0, ca), tt1 = fmaf(-va, v1, cb);               \
        v0 = fmaf(cosc, v0, sf * tt0);                                        \
        v1 = fmaf(cosc, v1, sf * tt1);                                        \
        {                                                                     \
            float nvE0 = frl(v0, 0), nvE1 = frl(v1, 0);                       \
            float ns = copysignf(1.0f, nvE0);                                 \
            rcp_v = __builtin_amdgcn_rcpf(nvE0 + ns);                         \
            vE0 = nvE0; vE1s = nvE1 * ns;                                     \
        }                                                                     \
        x0 = fmaf(dstep, v0, x0); x1 = fmaf(dstep, v1, x1);                   \
        xrow += 64;                                                           \
        uint_t pk; asm("v_cvt_pk_bf16_f32 %0, %1, %2" : "=v"(pk) : "v"(x0), "v"(x1)); \
        xrow[lane] = pk;                                                      \
        if (DO_PF) {                                                          \
            const char* g = ag + ((i) + 8) * 508;                             \
            char* slot = (char*)&ring[(((i) + 8) & 15) * 128];                \
            int o2 = ((i) == 117) ? 252 : 256;  /* avoid 4B OOB on row 125 */ \
            load_lds4(g + 4 * lane, slot);                                    \
            load_lds4(g + o2 + 4 * lane, slot + o2);                          \
        }                                                                     \
    }

    #pragma unroll 1
    for (int i = 0; i < 118; ++i) STEP(i, 1, 1)

    asm volatile("s_waitcnt vmcnt(0)" ::: "memory");
    #pragma unroll 1
    for (int i = 118; i < 126; ++i) STEP(i, 0, 0)
#undef STEP
}

// ---------------------------------------------------------------------------
// Kernel 2: MFMA gram (single 32KB bf16 LDS stage) + B-S tail log-lik.
// 4 waves; wave w owns tile-rows {w, 7-w} via template<int W> (acc = 9 f4).
// ---------------------------------------------------------------------------
__device__ __forceinline__ bfrag ldfrag(const ushort_t* base, int row, int kelem) {
    int byte = ((row << 8) + (kelem << 1)) ^ ((row & 7) << 4);
    return *(const bfrag*)((const char*)base + byte);
}

template<int W>
__device__ __forceinline__ void gram_w(const ushort_t* Xs, f4 (&acc)[9],
                                       int lr, int lg) {
    constexpr int RA = W, RB = 7 - W;
    #pragma unroll
    for (int ks = 0; ks < 4; ++ks) {
        const int kb = ks * 32 + lg * 8;
        const bfrag ha = ldfrag(Xs, RA * 16 + lr, kb);
        const bfrag hb = ldfrag(Xs, RB * 16 + lr, kb);
        #pragma unroll
        for (int TC = W; TC < 8; ++TC) {
            const bfrag bh = ldfrag(Xs, TC * 16 + lr, kb);
            acc[TC - W] = __builtin_amdgcn_mfma_f32_16x16x32_bf16(ha, bh, acc[TC - W], 0, 0, 0);
            if (TC >= RB)
                acc[TC + 1] = __builtin_amdgcn_mfma_f32_16x16x32_bf16(hb, bh, acc[TC + 1], 0, 0, 0);
        }
    }
}

template<int W>
__device__ __forceinline__ void write_sq(const f4 (&acc)[9], float* sq, int lr, int lg) {
    #pragma unroll
    for (int q = 0; q < 4; ++q) {
        if (4 * lg + q == lr) {
            sq[W * 16 + lr]       = acc[0][q];       // tile (W,W)
            sq[(7 - W) * 16 + lr] = acc[8 - W][q];   // tile (7-W,7-W)
        }
    }
}

// Borjesson-Sundberg Q(z) ~ phi(z)/((1-A)z + A*sqrt(z^2+B)); rel err <~0.5%.
// q_axb = F1 + F2 - 2 F1 F2 is relative-accurate (no cancellation).
__device__ __forceinline__ float entry_ll(float g, float sqn, float sqm,
        uint_t cw, float lam, float one_m2l) {
    const float d2 = fmaxf(sqn + sqm - 2.0f * g, 0.0f);
    const float pd = __builtin_amdgcn_sqrtf(d2);
    const float A = 0.344f, B = 5.334f, IA = 0.656f, C = 0.3989422804f;
    const float z1 = 0.70710678f * pd, z2 = 0.5f * pd;
    const float e1 = __expf(-0.25f  * d2) * C;   // phi(z1)
    const float e2 = __expf(-0.125f * d2) * C;   // phi(z2)
    const float den1 = fmaf(A, __builtin_amdgcn_sqrtf(fmaf(0.5f,  d2, B)), IA * z1);
    const float den2 = fmaf(A, __builtin_amdgcn_sqrtf(fmaf(0.25f, d2, B)), IA * z2);
    const float F1 = e1 * __builtin_amdgcn_rcpf(den1);
    const float F2 = e2 * __builtin_amdgcn_rcpf(den2);
    const float qax = F1 + F2 - 2.0f * F1 * F2;
    float qp = fmaf(one_m2l, qax, lam);
    qp = fminf(fmaxf(qp, 1e-7f), 1.0f - 1e-7f);
    const float pp = 1.0f - qp;
    const float c   = bf2f((ushort_t)(cw & 0xffffu));
    const float amc = bf2f((ushort_t)(cw >> 16));
    return c * __logf(pp) + amc * __logf(qp);
}

__device__ __forceinline__ float tile_ll(f4 a, int TR, int TC, bool diag,
        int lr, int lg, const float* sq, const uint_t* __restrict__ cnt,
        float lam, float one_m2l) {
    float s = 0.0f;
    #pragma unroll
    for (int q = 0; q < 4; ++q) {
        const int n = TR * 16 + 4 * lg + q;
        const int m = TC * 16 + lr;
        if (!diag || (4 * lg + q) <= lr)
            s += entry_ll(a[q], sq[n], sq[m], cnt[n * 128 + m], lam, one_m2l);
    }
    return s;
}

template<int W>
__device__ __forceinline__ float epi(const f4 (&acc)[9], const float* sq,
        const uint_t* __restrict__ cnt, int lr, int lg, float lam, float one_m2l) {
    constexpr int RA = W, RB = 7 - W;
    float s = 0.0f;
    #pragma unroll
    for (int TC = W; TC < 8; ++TC) {
        s += tile_ll(acc[TC - W], RA, TC, (TC == RA), lr, lg, sq, cnt, lam, one_m2l);
        if (TC >= RB)
            s += tile_ll(acc[TC + 1], RB, TC, (TC == RB), lr, lg, sq, cnt, lam, one_m2l);
    }
    return s;
}

__global__ __launch_bounds__(256, 4) void ll_kernel(
        const uint_t* __restrict__ x_g,
        const float* __restrict__ l_raw, const uint_t* __restrict__ cnt,
        float* __restrict__ sums, int s_base) {
    const int li = blockIdx.x;
    const int s  = s_base + li;
    const int t  = threadIdx.x;

    __shared__ __align__(16) ushort_t Xs[NNODES * 128];   // 32 KB
    __shared__ float sq[NNODES];
    __shared__ float wsum[4];

    const uint_t* gx = x_g + (size_t)li * NNODES * 64;
    const int l = t & 63, w = t >> 6, lr = l & 15, lg = l >> 4;

    // fill LDS (swizzled) with 16B chunks; 2048 chunks over 256 threads
    #pragma unroll
    for (int ii = 0; ii < 8; ++ii) {
        const int i = t + ii * 256;
        const int row = i >> 4, j = i & 15;
        const uint4 v = *(const uint4*)(gx + row * 64 + j * 4);
        const int b = ((row << 8) + (j << 4)) ^ ((row & 7) << 4);
        *(uint4*)((char*)Xs + b) = v;
    }
    __syncthreads();

    f4 acc[9];
    #pragma unroll
    for (int i = 0; i < 9; ++i) acc[i] = (f4)(0.0f);

    switch (w) {
        case 0: gram_w<0>(Xs, acc, lr, lg); write_sq<0>(acc, sq, lr, lg); break;
        case 1: gram_w<1>(Xs, acc, lr, lg); write_sq<1>(acc, sq, lr, lg); break;
        case 2: gram_w<2>(Xs, acc, lr, lg); write_sq<2>(acc, sq, lr, lg); break;
        default: gram_w<3>(Xs, acc, lr, lg); write_sq<3>(acc, sq, lr, lg); break;
    }
    __syncthreads();

    const float lam = 0.06f * normal_cdf_f(l_raw[s]);
    const float one_m2l = 1.0f - 2.0f * lam;
    float ll = 0.0f;
    switch (w) {
        case 0: ll = epi<0>(acc, sq, cnt, lr, lg, lam, one_m2l); break;
        case 1: ll = epi<1>(acc, sq, cnt, lr, lg, lam, one_m2l); break;
        case 2: ll = epi<2>(acc, sq, cnt, lr, lg, lam, one_m2l); break;
        default: ll = epi<3>(acc, sq, cnt, lr, lg, lam, one_m2l); break;
    }

    const float wtot = wave_sum(ll);
    if (l == 0) wsum[w] = wtot;
    __syncthreads();
    if (t == 0) sums[s] = wsum[0] + wsum[1] + wsum[2] + wsum[3];
}

// ---------------------------------------------------------------------------
// Kernel 3: deterministic mean over S
// ---------------------------------------------------------------------------
__global__ __launch_bounds__(256) void reduce_kernel(
        const float* __restrict__ sums, float* __restrict__ out) {
    __shared__ double sh[256];
    const int t = threadIdx.x;
    double acc = 0.0;
    for (int i = t; i < S_TOT; i += 256) acc += (double)sums[i];
    sh[t] = acc;
    __syncthreads();
    for (int off = 128; off > 0; off >>= 1) {
        if (t < off) sh[t] += sh[t + off];
        __syncthreads();
    }
    if (t == 0) out[0] = (float)(sh[0] / (double)S_TOT);
}

// ---------------------------------------------------------------------------
extern "C" void kernel_launch(void* const* d_in, const int* in_sizes, int n_in,
                              void* d_out, int out_size, void* d_ws, size_t ws_size,
                              hipStream_t stream) {
    (void)in_sizes; (void)n_in; (void)out_size;
    const float* d_raw = (const float*)d_in[0];
    const float* c_raw = (const float*)d_in[1];
    const float* a_raw = (const float*)d_in[2];
    const float* l_raw = (const float*)d_in[3];
    const int*   all_t = (const int*)d_in[4];
    const int*   cor_t = (const int*)d_in[5];
    float* out = (float*)d_out;

    char*   ws   = (char*)d_ws;
    float*  sums = (float*)ws;                        // 8 KB
    uint_t* cnt  = (uint_t*)(ws + 8192);              // 64 KB packed counts
    char*   xbase = ws + 8192 + 65536;
    const size_t per_sample = (size_t)NNODES * 64 * sizeof(uint_t);  // 32 KB

    const size_t head = 8192 + 65536;
    size_t avail = (ws_size > head) ? ws_size - head : 0;
    int chunk = (int)(avail / per_sample);
    if (chunk > S_TOT) chunk = S_TOT;
    if (chunk < 1) chunk = 1;

    prep_counts<<<64, 256, 0, stream>>>(all_t, cor_t, cnt);

    for (int s0 = 0; s0 < S_TOT; s0 += chunk) {
        const int nblk = (S_TOT - s0 < chunk) ? (S_TOT - s0) : chunk;
        uint_t* xbuf = (uint_t*)xbase;
        traj_kernel<<<nblk, 64, 0, stream>>>(d_raw, c_raw, a_raw, xbuf, s0);
        ll_kernel<<<nblk, 256, 0, stream>>>(xbuf, l_raw, cnt, sums, s0);
    }
    reduce_kernel<<<1, 256, 0, stream>>>(sums, out);
}

// Round 7
// 109.799 us; speedup vs baseline: 6.0209x; 1.0469x over previous
//
#include <hip/hip_runtime.h>
#include <math.h>

#define S_TOT   2048
#define NNODES  128
#define D_DIM   127
#define N_STEPS 126

typedef unsigned short ushort_t;
typedef unsigned int   uint_t;
typedef __attribute__((ext_vector_type(8))) short bfrag;   // 8 bf16 = 4 VGPR
typedef __attribute__((ext_vector_type(4))) float f4;

__device__ __forceinline__ float softplus_f(float x) {
    return log1pf(expf(-fabsf(x))) + fmaxf(x, 0.0f);
}
__device__ __forceinline__ float normal_cdf_f(float x) {
    return 0.5f * (1.0f + erff(x * 0.7071067811865475f));
}
__device__ __forceinline__ float frl(float x, int lane) {
    return __int_as_float(__builtin_amdgcn_readlane(__float_as_int(x), lane));
}
// 64-lane sum via DPP; returns wave-uniform total.
__device__ __forceinline__ float wave_sum(float x) {
    float r = x; int v;
    v = __builtin_amdgcn_update_dpp(0, __float_as_int(r), 0x111, 0xf, 0xf, true); r += __int_as_float(v);
    v = __builtin_amdgcn_update_dpp(0, __float_as_int(r), 0x112, 0xf, 0xf, true); r += __int_as_float(v);
    v = __builtin_amdgcn_update_dpp(0, __float_as_int(r), 0x114, 0xf, 0xf, true); r += __int_as_float(v);
    v = __builtin_amdgcn_update_dpp(0, __float_as_int(r), 0x118, 0xf, 0xf, true); r += __int_as_float(v);
    v = __builtin_amdgcn_update_dpp(0, __float_as_int(r), 0x142, 0xa, 0xf, true); r += __int_as_float(v);
    v = __builtin_amdgcn_update_dpp(0, __float_as_int(r), 0x143, 0xc, 0xf, true); r += __int_as_float(v);
    return frl(r, 63);
}
__device__ __forceinline__ ushort_t f2bf(float x) {        // RNE fp32 -> bf16
    uint_t u = __float_as_uint(x);
    uint_t r = u + 0x7fffu + ((u >> 16) & 1u);
    return (ushort_t)(r >> 16);
}
__device__ __forceinline__ float bf2f(ushort_t h) {
    return __uint_as_float(((uint_t)h) << 16);
}

// ---------------------------------------------------------------------------
// Kernel 0: symmetrized counts packed as bf16 pair: lo = csym, hi = asym-csym
// ---------------------------------------------------------------------------
__global__ __launch_bounds__(256) void prep_counts(
        const int* __restrict__ all_t, const int* __restrict__ cor_t,
        uint_t* __restrict__ pk) {
    int i = blockIdx.x * 256 + threadIdx.x;       // 16384
    int n = i >> 7, m = i & 127;
    int at = all_t[i], ct = cor_t[i];
    if (n != m) { at += all_t[m * 128 + n]; ct += cor_t[m * 128 + n]; }
    pk[i] = (uint_t)f2bf((float)ct) | ((uint_t)f2bf((float)(at - ct)) << 16);
}

// ---------------------------------------------------------------------------
// Kernel 1: trajectory. One wave per sample; lane l owns dims 2l, 2l+1.
// a-rows stream in groups of 16: plain global loads into 32 named regs,
// ds_write to a 32-row LDS ring one phase (16 steps) later, then consumed
// via ds_read one step ahead of use. No vmem asm; all ordering is plain
// data / LDS dependencies the compiler models exactly (T14 pattern).
// ---------------------------------------------------------------------------
#define LDROW(dstA, dstB, row)                                                \
    { const float* _p = ap + (size_t)(row) * D_DIM + 2 * lane;                \
      dstA = _p[0];                                                           \
      float _t = _p[d1ok ? 1 : 0];   /* clamped in-bounds, masked below */    \
      dstB = d1ok ? _t : 0.0f; }

#define STEP_CHAIN()                                                          \
    { const float ca = car, cb = cbm, aa = aa_n;                              \
      const float aE0 = aE0n, aE1 = aE1n;                                     \
      const float cosc = cosc_n, sinc = sinc_n, dstep = dstep_n;              \
      float va = wave_sum(fmaf(v0, ca, v1 * cb));                             \
      float ua = fmaf(fmaf(-vE0, aE0, va), rcp_v, aE0);                       \
      float w1 = fmaf(-ua, vE1s, aE1);                                        \
      float inv = __builtin_amdgcn_rsqf(fmaf(-va, va, aa));                   \
      float invs = (w1 >= 0.0f) ? -inv : inv;                                 \
      float sf = sinc * invs;                                                 \
      float tt0 = fmaf(-va, v0, ca), tt1 = fmaf(-va, v1, cb);                 \
      v0 = fmaf(cosc, v0, sf * tt0);                                          \
      v1 = fmaf(cosc, v1, sf * tt1);                                          \
      { float nv0 = frl(v0, 0), nv1 = frl(v1, 0);                             \
        float ns = copysignf(1.0f, nv0);                                      \
        rcp_v = __builtin_amdgcn_rcpf(nv0 + ns);                              \
        vE0 = nv0; vE1s = nv1 * ns; }                                         \
      x0 = fmaf(dstep, v0, x0); x1 = fmaf(dstep, v1, x1);                     \
      xp += 64;                                                               \
      uint_t pk;                                                              \
      asm("v_cvt_pk_bf16_f32 %0, %1, %2" : "=v"(pk) : "v"(x0), "v"(x1));      \
      xp[lane] = pk; }

#define NEXT_PRE(n)                                                           \
    { float2 nx = *(float2*)&abuf[(n) & 31][2 * lane];                        \
      car = nx.x; cbm = nx.y;        /* pad dim already zeroed at staging */  \
      aa_n = wave_sum(fmaf(car, car, cbm * cbm));                             \
      aE0n = frl(car, 0); aE1n = frl(cbm, 0);                                 \
      const float cv = cls[n];                                                \
      cosc_n = __cosf(cv); sinc_n = __sinf(cv);                               \
      dstep_n = dls[(n) + 1]; }

__global__ __launch_bounds__(64, 2) void traj_kernel(
        const float* __restrict__ d_raw, const float* __restrict__ c_raw,
        const float* __restrict__ a_raw,
        uint_t* __restrict__ xout, int s_base) {
    const int li = blockIdx.x;
    const int s  = s_base + li;
    const int lane = threadIdx.x;
    const bool d1ok = lane < 63;                  // dim 2l+1 <= 126

    __shared__ __align__(16) float abuf[32][128]; // 16 KB, 32-row ring
    __shared__ float dls[128];
    __shared__ float cls[128];

    // d (softplus'd) and c into LDS for uniform broadcast reads (padded 0)
    float t0 = softplus_f(d_raw[(size_t)s * D_DIM + lane]);
    dls[lane] = t0;
    dls[64 + lane] = d1ok ? softplus_f(d_raw[(size_t)s * D_DIM + 64 + lane]) : 0.0f;
    cls[lane] = c_raw[(size_t)s * N_STEPS + lane];
    cls[64 + lane] = (lane < 62) ? c_raw[(size_t)s * N_STEPS + 64 + lane] : 0.0f;

    const float* ap = a_raw + (size_t)s * N_STEPS * D_DIM;

    // group staging regs (static-indexed only)
    float ra0, ra1, ra2, ra3, ra4, ra5, ra6, ra7,
          ra8, ra9, ra10, ra11, ra12, ra13, ra14, ra15;
    float rb0, rb1, rb2, rb3, rb4, rb5, rb6, rb7,
          rb8, rb9, rb10, rb11, rb12, rb13, rb14, rb15;

#define LOAD_GROUP(base_row, GUARD)                                           \
    { const int _b = (base_row);                                              \
      if (!(GUARD) || _b + 0  < 126) LDROW(ra0,  rb0,  _b + 0)  else { ra0 = 0; rb0 = 0; }   \
      if (!(GUARD) || _b + 1  < 126) LDROW(ra1,  rb1,  _b + 1)  else { ra1 = 0; rb1 = 0; }   \
      if (!(GUARD) || _b + 2  < 126) LDROW(ra2,  rb2,  _b + 2)  else { ra2 = 0; rb2 = 0; }   \
      if (!(GUARD) || _b + 3  < 126) LDROW(ra3,  rb3,  _b + 3)  else { ra3 = 0; rb3 = 0; }   \
      if (!(GUARD) || _b + 4  < 126) LDROW(ra4,  rb4,  _b + 4)  else { ra4 = 0; rb4 = 0; }   \
      if (!(GUARD) || _b + 5  < 126) LDROW(ra5,  rb5,  _b + 5)  else { ra5 = 0; rb5 = 0; }   \
      if (!(GUARD) || _b + 6  < 126) LDROW(ra6,  rb6,  _b + 6)  else { ra6 = 0; rb6 = 0; }   \
      if (!(GUARD) || _b + 7  < 126) LDROW(ra7,  rb7,  _b + 7)  else { ra7 = 0; rb7 = 0; }   \
      if (!(GUARD) || _b + 8  < 126) LDROW(ra8,  rb8,  _b + 8)  else { ra8 = 0; rb8 = 0; }   \
      if (!(GUARD) || _b + 9  < 126) LDROW(ra9,  rb9,  _b + 9)  else { ra9 = 0; rb9 = 0; }   \
      if (!(GUARD) || _b + 10 < 126) LDROW(ra10, rb10, _b + 10) else { ra10 = 0; rb10 = 0; } \
      if (!(GUARD) || _b + 11 < 126) LDROW(ra11, rb11, _b + 11) else { ra11 = 0; rb11 = 0; } \
      if (!(GUARD) || _b + 12 < 126) LDROW(ra12, rb12, _b + 12) else { ra12 = 0; rb12 = 0; } \
      if (!(GUARD) || _b + 13 < 126) LDROW(ra13, rb13, _b + 13) else { ra13 = 0; rb13 = 0; } \
      if (!(GUARD) || _b + 14 < 126) LDROW(ra14, rb14, _b + 14) else { ra14 = 0; rb14 = 0; } \
      if (!(GUARD) || _b + 15 < 126) LDROW(ra15, rb15, _b + 15) else { ra15 = 0; rb15 = 0; } }

#define WRITE_GROUP(base_row)                                                 \
    { const int _sb = (base_row) & 31;                                        \
      *(float2*)&abuf[_sb + 0 ][2 * lane] = make_float2(ra0,  rb0);           \
      *(float2*)&abuf[_sb + 1 ][2 * lane] = make_float2(ra1,  rb1);           \
      *(float2*)&abuf[_sb + 2 ][2 * lane] = make_float2(ra2,  rb2);           \
      *(float2*)&abuf[_sb + 3 ][2 * lane] = make_float2(ra3,  rb3);           \
      *(float2*)&abuf[_sb + 4 ][2 * lane] = make_float2(ra4,  rb4);           \
      *(float2*)&abuf[_sb + 5 ][2 * lane] = make_float2(ra5,  rb5);           \
      *(float2*)&abuf[_sb + 6 ][2 * lane] = make_float2(ra6,  rb6);           \
      *(float2*)&abuf[_sb + 7 ][2 * lane] = make_float2(ra7,  rb7);           \
      *(float2*)&abuf[_sb + 8 ][2 * lane] = make_float2(ra8,  rb8);           \
      *(float2*)&abuf[_sb + 9 ][2 * lane] = make_float2(ra9,  rb9);           \
      *(float2*)&abuf[_sb + 10][2 * lane] = make_float2(ra10, rb10);          \
      *(float2*)&abuf[_sb + 11][2 * lane] = make_float2(ra11, rb11);          \
      *(float2*)&abuf[_sb + 12][2 * lane] = make_float2(ra12, rb12);          \
      *(float2*)&abuf[_sb + 13][2 * lane] = make_float2(ra13, rb13);          \
      *(float2*)&abuf[_sb + 14][2 * lane] = make_float2(ra14, rb14);          \
      *(float2*)&abuf[_sb + 15][2 * lane] = make_float2(ra15, rb15); }

    // prologue: stage G0, write it, stage G1 (written at boundary i=15)
    LOAD_GROUP(0, 0)
    WRITE_GROUP(0)
    LOAD_GROUP(16, 0)

    // init state
    float v0 = (lane == 0) ? 1.0f : 0.0f, v1 = 0.0f;
    float x0 = (lane == 0) ? t0 : 0.0f,  x1 = 0.0f;
    float vE0 = 1.0f, vE1s = 0.0f, rcp_v = 0.5f;   // v = e0 exactly

    uint_t* xp = xout + (size_t)li * NNODES * 64;
    xp[lane] = 0u;                                // row 0
    xp += 64;
    {
        uint_t pk0;
        asm("v_cvt_pk_bf16_f32 %0, %1, %2" : "=v"(pk0) : "v"(x0), "v"(x1));
        xp[lane] = pk0;                           // row 1
    }

    // next-state for iter 0 (row 0)
    float car, cbm, aa_n, aE0n, aE1n, cosc_n, sinc_n, dstep_n;
    NEXT_PRE(0)

    // main: 7 phases x 16 steps (i = 0..111)
    #pragma unroll 1
    for (int g = 0; g < 7; ++g) {
        #pragma unroll
        for (int j = 0; j < 16; ++j) {
            const int i = 16 * g + j;
            STEP_CHAIN()
            if (j == 15) {
                WRITE_GROUP(16 * (g + 1))          // rows loaded 16 steps ago
                if (g < 6) LOAD_GROUP(16 * (g + 2), 1)
            }
            NEXT_PRE(i + 1)
        }
    }
    // tail: steps 112..125 (G7 already written at i=111 boundary)
    #pragma unroll
    for (int j = 0; j < 14; ++j) {
        const int i = 112 + j;
        STEP_CHAIN()
        const int nn = (i + 1 < 125) ? (i + 1) : 125;
        NEXT_PRE(nn)
    }
#undef LOAD_GROUP
#undef WRITE_GROUP
}
#undef LDROW
#undef STEP_CHAIN
#undef NEXT_PRE

// ---------------------------------------------------------------------------
// Kernel 2: MFMA gram (single 32KB bf16 LDS stage) + B-S tail log-lik.
// 4 waves; wave w owns tile-rows {w, 7-w} via template<int W> (acc = 9 f4).
// ---------------------------------------------------------------------------
__device__ __forceinline__ bfrag ldfrag(const ushort_t* base, int row, int kelem) {
    int byte = ((row << 8) + (kelem << 1)) ^ ((row & 7) << 4);
    return *(const bfrag*)((const char*)base + byte);
}

template<int W>
__device__ __forceinline__ void gram_w(const ushort_t* Xs, f4 (&acc)[9],
                                       int lr, int lg) {
    constexpr int RA = W, RB = 7 - W;
    #pragma unroll
    for (int ks = 0; ks < 4; ++ks) {
        const int kb = ks * 32 + lg * 8;
        const bfrag ha = ldfrag(Xs, RA * 16 + lr, kb);
        const bfrag hb = ldfrag(Xs, RB * 16 + lr, kb);
        #pragma unroll
        for (int TC = W; TC < 8; ++TC) {
            const bfrag bh = ldfrag(Xs, TC * 16 + lr, kb);
            acc[TC - W] = __builtin_amdgcn_mfma_f32_16x16x32_bf16(ha, bh, acc[TC - W], 0, 0, 0);
            if (TC >= RB)
                acc[TC + 1] = __builtin_amdgcn_mfma_f32_16x16x32_bf16(hb, bh, acc[TC + 1], 0, 0, 0);
        }
    }
}

template<int W>
__device__ __forceinline__ void write_sq(const f4 (&acc)[9], float* sq, int lr, int lg) {
    #pragma unroll
    for (int q = 0; q < 4; ++q) {
        if (4 * lg + q == lr) {
            sq[W * 16 + lr]       = acc[0][q];       // tile (W,W)
            sq[(7 - W) * 16 + lr] = acc[8 - W][q];   // tile (7-W,7-W)
        }
    }
}

// Borjesson-Sundberg Q(z) ~ phi(z)/((1-A)z + A*sqrt(z^2+B)); rel err <~0.5%.
// q_axb = F1 + F2 - 2 F1 F2 is relative-accurate (no cancellation).
__device__ __forceinline__ float entry_ll(float g, float sqn, float sqm,
        uint_t cw, float lam, float one_m2l) {
    const float d2 = fmaxf(sqn + sqm - 2.0f * g, 0.0f);
    const float pd = __builtin_amdgcn_sqrtf(d2);
    const float A = 0.344f, B = 5.334f, IA = 0.656f, C = 0.3989422804f;
    const float z1 = 0.70710678f * pd, z2 = 0.5f * pd;
    const float e1 = __expf(-0.25f  * d2) * C;   // phi(z1)
    const float e2 = __expf(-0.125f * d2) * C;   // phi(z2)
    const float den1 = fmaf(A, __builtin_amdgcn_sqrtf(fmaf(0.5f,  d2, B)), IA * z1);
    const float den2 = fmaf(A, __builtin_amdgcn_sqrtf(fmaf(0.25f, d2, B)), IA * z2);
    const float F1 = e1 * __builtin_amdgcn_rcpf(den1);
    const float F2 = e2 * __builtin_amdgcn_rcpf(den2);
    const float qax = F1 + F2 - 2.0f * F1 * F2;
    float qp = fmaf(one_m2l, qax, lam);
    qp = fminf(fmaxf(qp, 1e-7f), 1.0f - 1e-7f);
    const float pp = 1.0f - qp;
    const float c   = bf2f((ushort_t)(cw & 0xffffu));
    const float amc = bf2f((ushort_t)(cw >> 16));
    return c * __logf(pp) + amc * __logf(qp);
}

__device__ __forceinline__ float tile_ll(f4 a, int TR, int TC, bool diag,
        int lr, int lg, const float* sq, const uint_t* __restrict__ cnt,
        float lam, float one_m2l) {
    float s = 0.0f;
    #pragma unroll
    for (int q = 0; q < 4; ++q) {
        const int n = TR * 16 + 4 * lg + q;
        const int m = TC * 16 + lr;
        if (!diag || (4 * lg + q) <= lr)
            s += entry_ll(a[q], sq[n], sq[m], cnt[n * 128 + m], lam, one_m2l);
    }
    return s;
}

template<int W>
__device__ __forceinline__ float epi(const f4 (&acc)[9], const float* sq,
        const uint_t* __restrict__ cnt, int lr, int lg, float lam, float one_m2l) {
    constexpr int RA = W, RB = 7 - W;
    float s = 0.0f;
    #pragma unroll
    for (int TC = W; TC < 8; ++TC) {
        s += tile_ll(acc[TC - W], RA, TC, (TC == RA), lr, lg, sq, cnt, lam, one_m2l);
        if (TC >= RB)
            s += tile_ll(acc[TC + 1], RB, TC, (TC == RB), lr, lg, sq, cnt, lam, one_m2l);
    }
    return s;
}

__global__ __launch_bounds__(256, 4) void ll_kernel(
        const uint_t* __restrict__ x_g,
        const float* __restrict__ l_raw, const uint_t* __restrict__ cnt,
        float* __restrict__ sums, int s_base) {
    const int li = blockIdx.x;
    const int s  = s_base + li;
    const int t  = threadIdx.x;

    __shared__ __align__(16) ushort_t Xs[NNODES * 128];   // 32 KB
    __shared__ float sq[NNODES];
    __shared__ float wsum[4];

    const uint_t* gx = x_g + (size_t)li * NNODES * 64;
    const int l = t & 63, w = t >> 6, lr = l & 15, lg = l >> 4;

    // fill LDS (swizzled) with 16B chunks; 2048 chunks over 256 threads
    #pragma unroll
    for (int ii = 0; ii < 8; ++ii) {
        const int i = t + ii * 256;
        const int row = i >> 4, j = i & 15;
        const uint4 v = *(const uint4*)(gx + row * 64 + j * 4);
        const int b = ((row << 8) + (j << 4)) ^ ((row & 7) << 4);
        *(uint4*)((char*)Xs + b) = v;
    }
    __syncthreads();

    f4 acc[9];
    #pragma unroll
    for (int i = 0; i < 9; ++i) acc[i] = (f4)(0.0f);

    switch (w) {
        case 0: gram_w<0>(Xs, acc, lr, lg); write_sq<0>(acc, sq, lr, lg); break;
        case 1: gram_w<1>(Xs, acc, lr, lg); write_sq<1>(acc, sq, lr, lg); break;
        case 2: gram_w<2>(Xs, acc, lr, lg); write_sq<2>(acc, sq, lr, lg); break;
        default: gram_w<3>(Xs, acc, lr, lg); write_sq<3>(acc, sq, lr, lg); break;
    }
    __syncthreads();

    const float lam = 0.06f * normal_cdf_f(l_raw[s]);
    const float one_m2l = 1.0f - 2.0f * lam;
    float ll = 0.0f;
    switch (w) {
        case 0: ll = epi<0>(acc, sq, cnt, lr, lg, lam, one_m2l); break;
        case 1: ll = epi<1>(acc, sq, cnt, lr, lg, lam, one_m2l); break;
        case 2: ll = epi<2>(acc, sq, cnt, lr, lg, lam, one_m2l); break;
        default: ll = epi<3>(acc, sq, cnt, lr, lg, lam, one_m2l); break;
    }

    const float wtot = wave_sum(ll);
    if (l == 0) wsum[w] = wtot;
    __syncthreads();
    if (t == 0) sums[s] = wsum[0] + wsum[1] + wsum[2] + wsum[3];
}

// ---------------------------------------------------------------------------
// Kernel 3: deterministic mean over S
// ---------------------------------------------------------------------------
__global__ __launch_bounds__(256) void reduce_kernel(
        const float* __restrict__ sums, float* __restrict__ out) {
    __shared__ double sh[256];
    const int t = threadIdx.x;
    double acc = 0.0;
    for (int i = t; i < S_TOT; i += 256) acc += (double)sums[i];
    sh[t] = acc;
    __syncthreads();
    for (int off = 128; off > 0; off >>= 1) {
        if (t < off) sh[t] += sh[t + off];
        __syncthreads();
    }
    if (t == 0) out[0] = (float)(sh[0] / (double)S_TOT);
}

// ---------------------------------------------------------------------------
extern "C" void kernel_launch(void* const* d_in, const int* in_sizes, int n_in,
                              void* d_out, int out_size, void* d_ws, size_t ws_size,
                              hipStream_t stream) {
    (void)in_sizes; (void)n_in; (void)out_size;
    const float* d_raw = (const float*)d_in[0];
    const float* c_raw = (const float*)d_in[1];
    const float* a_raw = (const float*)d_in[2];
    const float* l_raw = (const float*)d_in[3];
    const int*   all_t = (const int*)d_in[4];
    const int*   cor_t = (const int*)d_in[5];
    float* out = (float*)d_out;

    char*   ws   = (char*)d_ws;
    float*  sums = (float*)ws;                        // 8 KB
    uint_t* cnt  = (uint_t*)(ws + 8192);              // 64 KB packed counts
    char*   xbase = ws + 8192 + 65536;
    const size_t per_sample = (size_t)NNODES * 64 * sizeof(uint_t);  // 32 KB

    const size_t head = 8192 + 65536;
    size_t avail = (ws_size > head) ? ws_size - head : 0;
    int chunk = (int)(avail / per_sample);
    if (chunk > S_TOT) chunk = S_TOT;
    if (chunk < 1) chunk = 1;

    prep_counts<<<64, 256, 0, stream>>>(all_t, cor_t, cnt);

    for (int s0 = 0; s0 < S_TOT; s0 += chunk) {
        const int nblk = (S_TOT - s0 < chunk) ? (S_TOT - s0) : chunk;
        uint_t* xbuf = (uint_t*)xbase;
        traj_kernel<<<nblk, 64, 0, stream>>>(d_raw, c_raw, a_raw, xbuf, s0);
        ll_kernel<<<nblk, 256, 0, stream>>>(xbuf, l_raw, cnt, sums, s0);
    }
    reduce_kernel<<<1, 256, 0, stream>>>(sums, out);
}

// Round 8
// 109.384 us; speedup vs baseline: 6.0438x; 1.0038x over previous
//
#include <hip/hip_runtime.h>
#include <math.h>

#define S_TOT   2048
#define NNODES  128
#define D_DIM   127
#define N_STEPS 126

typedef unsigned short ushort_t;
typedef unsigned int   uint_t;
typedef __attribute__((ext_vector_type(8))) short bfrag;   // 8 bf16 = 4 VGPR
typedef __attribute__((ext_vector_type(4))) float f4;

__device__ __forceinline__ float softplus_f(float x) {
    return log1pf(expf(-fabsf(x))) + fmaxf(x, 0.0f);
}
__device__ __forceinline__ float normal_cdf_f(float x) {
    return 0.5f * (1.0f + erff(x * 0.7071067811865475f));
}
__device__ __forceinline__ float frl(float x, int lane) {
    return __int_as_float(__builtin_amdgcn_readlane(__float_as_int(x), lane));
}
// 64-lane sum via DPP; returns wave-uniform total.
__device__ __forceinline__ float wave_sum(float x) {
    float r = x; int v;
    v = __builtin_amdgcn_update_dpp(0, __float_as_int(r), 0x111, 0xf, 0xf, true); r += __int_as_float(v);
    v = __builtin_amdgcn_update_dpp(0, __float_as_int(r), 0x112, 0xf, 0xf, true); r += __int_as_float(v);
    v = __builtin_amdgcn_update_dpp(0, __float_as_int(r), 0x114, 0xf, 0xf, true); r += __int_as_float(v);
    v = __builtin_amdgcn_update_dpp(0, __float_as_int(r), 0x118, 0xf, 0xf, true); r += __int_as_float(v);
    v = __builtin_amdgcn_update_dpp(0, __float_as_int(r), 0x142, 0xa, 0xf, true); r += __int_as_float(v);
    v = __builtin_amdgcn_update_dpp(0, __float_as_int(r), 0x143, 0xc, 0xf, true); r += __int_as_float(v);
    return frl(r, 63);
}
__device__ __forceinline__ ushort_t f2bf(float x) {        // RNE fp32 -> bf16
    uint_t u = __float_as_uint(x);
    uint_t r = u + 0x7fffu + ((u >> 16) & 1u);
    return (ushort_t)(r >> 16);
}
__device__ __forceinline__ float bf2f(ushort_t h) {
    return __uint_as_float(((uint_t)h) << 16);
}

// ---------------------------------------------------------------------------
// Kernel 0: symmetrized counts packed as bf16 pair: lo = csym, hi = asym-csym
// ---------------------------------------------------------------------------
__global__ __launch_bounds__(256) void prep_counts(
        const int* __restrict__ all_t, const int* __restrict__ cor_t,
        uint_t* __restrict__ pk) {
    int i = blockIdx.x * 256 + threadIdx.x;       // 16384
    int n = i >> 7, m = i & 127;
    int at = all_t[i], ct = cor_t[i];
    if (n != m) { at += all_t[m * 128 + n]; ct += cor_t[m * 128 + n]; }
    pk[i] = (uint_t)f2bf((float)ct) | ((uint_t)f2bf((float)(at - ct)) << 16);
}

// ---------------------------------------------------------------------------
// Kernel 1: trajectory. One wave per sample; lane l owns dims 2l, 2l+1.
// Deep-pipelined: only wave_sum(v.a) is on the inter-step chain. Everything
// else (a-row ds_read, aa reduction, aE readlanes, cos/sin, dstep) is
// computed 2-3 steps ahead; pivots v[0],v[1] are lane-replicated (vp0,vp1)
// so no readlane of v is needed. a-rows staged in 16-row groups, loaded 32
// steps before their ds_write (structural HBM cover).
// ---------------------------------------------------------------------------
#define LDR1(A, B, row)                                                       \
    { const float* _p = ap + (size_t)(row) * D_DIM + 2 * lane;                \
      A = _p[0];                                                              \
      float _t = _p[d1ok ? 1 : 0];   /* lane63 stays in-bounds */             \
      B = d1ok ? _t : 0.0f; }

#define LOAD_G(BASE, GUARD)                                                   \
    { const int _b = (BASE); const bool _gd = (GUARD);                        \
      if (!_gd || _b + 0  < 126) LDR1(sa0,  sb0,  _b + 0)  else { sa0 = 0; sb0 = 0; }   \
      if (!_gd || _b + 1  < 126) LDR1(sa1,  sb1,  _b + 1)  else { sa1 = 0; sb1 = 0; }   \
      if (!_gd || _b + 2  < 126) LDR1(sa2,  sb2,  _b + 2)  else { sa2 = 0; sb2 = 0; }   \
      if (!_gd || _b + 3  < 126) LDR1(sa3,  sb3,  _b + 3)  else { sa3 = 0; sb3 = 0; }   \
      if (!_gd || _b + 4  < 126) LDR1(sa4,  sb4,  _b + 4)  else { sa4 = 0; sb4 = 0; }   \
      if (!_gd || _b + 5  < 126) LDR1(sa5,  sb5,  _b + 5)  else { sa5 = 0; sb5 = 0; }   \
      if (!_gd || _b + 6  < 126) LDR1(sa6,  sb6,  _b + 6)  else { sa6 = 0; sb6 = 0; }   \
      if (!_gd || _b + 7  < 126) LDR1(sa7,  sb7,  _b + 7)  else { sa7 = 0; sb7 = 0; }   \
      if (!_gd || _b + 8  < 126) LDR1(sa8,  sb8,  _b + 8)  else { sa8 = 0; sb8 = 0; }   \
      if (!_gd || _b + 9  < 126) LDR1(sa9,  sb9,  _b + 9)  else { sa9 = 0; sb9 = 0; }   \
      if (!_gd || _b + 10 < 126) LDR1(sa10, sb10, _b + 10) else { sa10 = 0; sb10 = 0; } \
      if (!_gd || _b + 11 < 126) LDR1(sa11, sb11, _b + 11) else { sa11 = 0; sb11 = 0; } \
      if (!_gd || _b + 12 < 126) LDR1(sa12, sb12, _b + 12) else { sa12 = 0; sb12 = 0; } \
      if (!_gd || _b + 13 < 126) LDR1(sa13, sb13, _b + 13) else { sa13 = 0; sb13 = 0; } \
      if (!_gd || _b + 14 < 126) LDR1(sa14, sb14, _b + 14) else { sa14 = 0; sb14 = 0; } \
      if (!_gd || _b + 15 < 126) LDR1(sa15, sb15, _b + 15) else { sa15 = 0; sb15 = 0; } }

#define WRITE_G(SB)                                                           \
    { const int _s = (SB);                                                    \
      *(float2*)&abuf[_s + 0 ][2 * lane] = make_float2(sa0,  sb0);            \
      *(float2*)&abuf[_s + 1 ][2 * lane] = make_float2(sa1,  sb1);            \
      *(float2*)&abuf[_s + 2 ][2 * lane] = make_float2(sa2,  sb2);            \
      *(float2*)&abuf[_s + 3 ][2 * lane] = make_float2(sa3,  sb3);            \
      *(float2*)&abuf[_s + 4 ][2 * lane] = make_float2(sa4,  sb4);            \
      *(float2*)&abuf[_s + 5 ][2 * lane] = make_float2(sa5,  sb5);            \
      *(float2*)&abuf[_s + 6 ][2 * lane] = make_float2(sa6,  sb6);            \
      *(float2*)&abuf[_s + 7 ][2 * lane] = make_float2(sa7,  sb7);            \
      *(float2*)&abuf[_s + 8 ][2 * lane] = make_float2(sa8,  sb8);            \
      *(float2*)&abuf[_s + 9 ][2 * lane] = make_float2(sa9,  sb9);            \
      *(float2*)&abuf[_s + 10][2 * lane] = make_float2(sa10, sb10);           \
      *(float2*)&abuf[_s + 11][2 * lane] = make_float2(sa11, sb11);           \
      *(float2*)&abuf[_s + 12][2 * lane] = make_float2(sa12, sb12);           \
      *(float2*)&abuf[_s + 13][2 * lane] = make_float2(sa13, sb13);           \
      *(float2*)&abuf[_s + 14][2 * lane] = make_float2(sa14, sb14);           \
      *(float2*)&abuf[_s + 15][2 * lane] = make_float2(sa15, sb15); }

// SC: ring slot of current row; SA: slot of row i+2 (aa/aE precompute);
// SR: slot to refill with row i+3; ROWRD: abuf row index for the refill;
// CLSI/DLSI: cos-sin / dstep lookahead indices.
#define STEP_CORE(SC, SA, SR, ROWRD, CLSI, DLSI)                              \
    {                                                                         \
        const float ca = ra_r[SC], cb = rb_r[SC];                             \
        /* --- inter-step critical chain --- */                               \
        float va = wave_sum(fmaf(v0, ca, v1 * cb));                           \
        float ua = fmaf(fmaf(-vp0, aE0U, va), rcp_v, aE0U);                   \
        float w1 = fmaf(-ua, vp1s, aE1U);                                     \
        float inv = __builtin_amdgcn_rsqf(fmaf(-va, va, aaU));                \
        float invs = (w1 >= 0.0f) ? -inv : inv;                               \
        float sf = sU * invs;                                                 \
        float nv0 = fmaf(cU, v0, sf * fmaf(-va, v0, ca));                     \
        float nv1 = fmaf(cU, v1, sf * fmaf(-va, v1, cb));                     \
        float np0 = fmaf(cU, vp0, sf * fmaf(-va, vp0, aE0U));                 \
        float np1 = fmaf(cU, vp1, sf * fmaf(-va, vp1, aE1U));                 \
        v0 = nv0; v1 = nv1; vp0 = np0; vp1 = np1;                             \
        { float ns = copysignf(1.0f, vp0);                                    \
          rcp_v = __builtin_amdgcn_rcpf(vp0 + ns); vp1s = vp1 * ns; }         \
        x0 = fmaf(dU, v0, x0); x1 = fmaf(dU, v1, x1);                         \
        { uint_t pk;                                                          \
          asm("v_cvt_pk_bf16_f32 %0, %1, %2" : "=v"(pk) : "v"(x0), "v"(x1));  \
          xp += 64; xp[lane] = pk; }                                          \
        /* --- off-chain: shift + refill pipelines --- */                     \
        aaU = aa1; aE0U = aE0_1; aE1U = aE1_1; cU = c1; sU = s1; dU = d1;     \
        aa1 = wave_sum(fmaf(ra_r[SA], ra_r[SA], rb_r[SA] * rb_r[SA]));        \
        aE0_1 = frl(ra_r[SA], 0); aE1_1 = frl(rb_r[SA], 0);                   \
        { float2 cs = cls2[CLSI]; c1 = cs.x; s1 = cs.y; }                     \
        d1 = dls[DLSI];                                                       \
        { float2 nx = *(float2*)&abuf[ROWRD][2 * lane];                       \
          ra_r[SR] = nx.x; rb_r[SR] = nx.y; }                                 \
    }

#define MSTEP(J) STEP_CORE((J) & 3, ((J) + 2) & 3, ((J) + 3) & 3,             \
                           (ib + (J) + 3) & 31, ib + (J) + 2, ib + (J) + 3)
#define TSTEP(J) STEP_CORE((J) & 3, ((J) + 2) & 3, ((J) + 3) & 3,             \
                           ((115 + (J) < 125) ? (115 + (J)) : 125) & 31,      \
                           ((114 + (J) < 127) ? (114 + (J)) : 127),           \
                           ((115 + (J) < 127) ? (115 + (J)) : 127))

__global__ __launch_bounds__(64, 2) void traj_kernel(
        const float* __restrict__ d_raw, const float* __restrict__ c_raw,
        const float* __restrict__ a_raw,
        uint_t* __restrict__ xout, int s_base) {
    const int li = blockIdx.x;
    const int s  = s_base + li;
    const int lane = threadIdx.x;
    const bool d1ok = lane < 63;                  // dim 2l+1 <= 126

    __shared__ __align__(16) float abuf[32][128]; // 16 KB (2 groups x 16 rows)
    __shared__ float  dls[128];
    __shared__ float2 cls2[128];

    // d (softplus'd), cos/sin tables for uniform broadcast reads (padded 0)
    float t0 = softplus_f(d_raw[(size_t)s * D_DIM + lane]);
    dls[lane] = t0;
    dls[64 + lane] = d1ok ? softplus_f(d_raw[(size_t)s * D_DIM + 64 + lane]) : 0.0f;
    {
        float cv = c_raw[(size_t)s * N_STEPS + lane];
        cls2[lane] = make_float2(__cosf(cv), __sinf(cv));
        if (lane < 62) {
            float cv2 = c_raw[(size_t)s * N_STEPS + 64 + lane];
            cls2[64 + lane] = make_float2(__cosf(cv2), __sinf(cv2));
        } else {
            cls2[64 + lane] = make_float2(0.0f, 0.0f);
        }
    }

    const float* ap = a_raw + (size_t)s * N_STEPS * D_DIM;

    // staging regs: one 16-row group
    float sa0, sa1, sa2, sa3, sa4, sa5, sa6, sa7,
          sa8, sa9, sa10, sa11, sa12, sa13, sa14, sa15;
    float sb0, sb1, sb2, sb3, sb4, sb5, sb6, sb7,
          sb8, sb9, sb10, sb11, sb12, sb13, sb14, sb15;

    // prologue: G0,G1 staged+written; G2 loaded (written at B_0)
    LOAD_G(0, false)  WRITE_G(0)
    LOAD_G(16, false) WRITE_G(16)
    LOAD_G(32, false)

    // ring (rows i..i+3) + pipelines primed for steps 0,1
    float ra_r[4], rb_r[4];
    { float2 t = *(float2*)&abuf[0][2 * lane]; ra_r[0] = t.x; rb_r[0] = t.y; }
    { float2 t = *(float2*)&abuf[1][2 * lane]; ra_r[1] = t.x; rb_r[1] = t.y; }
    { float2 t = *(float2*)&abuf[2][2 * lane]; ra_r[2] = t.x; rb_r[2] = t.y; }
    ra_r[3] = 0.0f; rb_r[3] = 0.0f;
    float aaU = wave_sum(fmaf(ra_r[0], ra_r[0], rb_r[0] * rb_r[0]));
    float aa1 = wave_sum(fmaf(ra_r[1], ra_r[1], rb_r[1] * rb_r[1]));
    float aE0U = frl(ra_r[0], 0), aE1U = frl(rb_r[0], 0);
    float aE0_1 = frl(ra_r[1], 0), aE1_1 = frl(rb_r[1], 0);
    float cU, sU, c1, s1;
    { float2 cs = cls2[0]; cU = cs.x; sU = cs.y; }
    { float2 cs = cls2[1]; c1 = cs.x; s1 = cs.y; }
    float dU = dls[1], d1 = dls[2];

    // state: v (lane dims), replicated pivots, x
    float v0 = (lane == 0) ? 1.0f : 0.0f, v1 = 0.0f;
    float vp0 = 1.0f, vp1 = 0.0f, vp1s = 0.0f, rcp_v = 0.5f;
    float x0 = (lane == 0) ? t0 : 0.0f, x1 = 0.0f;

    uint_t* xp = xout + (size_t)li * NNODES * 64;
    xp[lane] = 0u;                                // row 0
    {
        uint_t pk0;
        asm("v_cvt_pk_bf16_f32 %0, %1, %2" : "=v"(pk0) : "v"(x0), "v"(x1));
        xp += 64; xp[lane] = pk0;                 // row 1
    }

    // main: 7 groups x 16 steps (i = 0..111)
    #pragma unroll 1
    for (int g = 0; g < 7; ++g) {
        const int ib = g << 4;
        MSTEP(0)  MSTEP(1)  MSTEP(2)  MSTEP(3)
        MSTEP(4)  MSTEP(5)  MSTEP(6)  MSTEP(7)
        MSTEP(8)  MSTEP(9)  MSTEP(10) MSTEP(11)
        MSTEP(12) MSTEP(13) MSTEP(14) MSTEP(15)
        if (g <= 5) { WRITE_G((g & 1) << 4) }     // write G_{g+2}
        if (g <= 4) LOAD_G((g + 3) << 4, g == 4)  // load  G_{g+3}
    }
    // tail: steps 112..125
    TSTEP(0)  TSTEP(1)  TSTEP(2)  TSTEP(3)
    TSTEP(4)  TSTEP(5)  TSTEP(6)  TSTEP(7)
    TSTEP(8)  TSTEP(9)  TSTEP(10) TSTEP(11)
    TSTEP(12) TSTEP(13)
}
#undef MSTEP
#undef TSTEP
#undef STEP_CORE
#undef LOAD_G
#undef WRITE_G
#undef LDR1

// ---------------------------------------------------------------------------
// Kernel 2: MFMA gram (single 32KB bf16 LDS stage) + B-S tail log-lik.
// 4 waves; wave w owns tile-rows {w, 7-w} via template<int W> (acc = 9 f4).
// ---------------------------------------------------------------------------
__device__ __forceinline__ bfrag ldfrag(const ushort_t* base, int row, int kelem) {
    int byte = ((row << 8) + (kelem << 1)) ^ ((row & 7) << 4);
    return *(const bfrag*)((const char*)base + byte);
}

template<int W>
__device__ __forceinline__ void gram_w(const ushort_t* Xs, f4 (&acc)[9],
                                       int lr, int lg) {
    constexpr int RA = W, RB = 7 - W;
    #pragma unroll
    for (int ks = 0; ks < 4; ++ks) {
        const int kb = ks * 32 + lg * 8;
        const bfrag ha = ldfrag(Xs, RA * 16 + lr, kb);
        const bfrag hb = ldfrag(Xs, RB * 16 + lr, kb);
        #pragma unroll
        for (int TC = W; TC < 8; ++TC) {
            const bfrag bh = ldfrag(Xs, TC * 16 + lr, kb);
            acc[TC - W] = __builtin_amdgcn_mfma_f32_16x16x32_bf16(ha, bh, acc[TC - W], 0, 0, 0);
            if (TC >= RB)
                acc[TC + 1] = __builtin_amdgcn_mfma_f32_16x16x32_bf16(hb, bh, acc[TC + 1], 0, 0, 0);
        }
    }
}

template<int W>
__device__ __forceinline__ void write_sq(const f4 (&acc)[9], float* sq, int lr, int lg) {
    #pragma unroll
    for (int q = 0; q < 4; ++q) {
        if (4 * lg + q == lr) {
            sq[W * 16 + lr]       = acc[0][q];       // tile (W,W)
            sq[(7 - W) * 16 + lr] = acc[8 - W][q];   // tile (7-W,7-W)
        }
    }
}

// Borjesson-Sundberg Q(z) ~ phi(z)/((1-A)z + A*sqrt(z^2+B)); rel err <~0.5%.
// q_axb = F1 + F2 - 2 F1 F2 is relative-accurate (no cancellation).
__device__ __forceinline__ float entry_ll(float g, float sqn, float sqm,
        uint_t cw, float lam, float one_m2l) {
    const float d2 = fmaxf(sqn + sqm - 2.0f * g, 0.0f);
    const float pd = __builtin_amdgcn_sqrtf(d2);
    const float A = 0.344f, B = 5.334f, IA = 0.656f, C = 0.3989422804f;
    const float z1 = 0.70710678f * pd, z2 = 0.5f * pd;
    const float e1 = __expf(-0.25f  * d2) * C;   // phi(z1)
    const float e2 = __expf(-0.125f * d2) * C;   // phi(z2)
    const float den1 = fmaf(A, __builtin_amdgcn_sqrtf(fmaf(0.5f,  d2, B)), IA * z1);
    const float den2 = fmaf(A, __builtin_amdgcn_sqrtf(fmaf(0.25f, d2, B)), IA * z2);
    const float F1 = e1 * __builtin_amdgcn_rcpf(den1);
    const float F2 = e2 * __builtin_amdgcn_rcpf(den2);
    const float qax = F1 + F2 - 2.0f * F1 * F2;
    float qp = fmaf(one_m2l, qax, lam);
    qp = fminf(fmaxf(qp, 1e-7f), 1.0f - 1e-7f);
    const float pp = 1.0f - qp;
    const float c   = bf2f((ushort_t)(cw & 0xffffu));
    const float amc = bf2f((ushort_t)(cw >> 16));
    return c * __logf(pp) + amc * __logf(qp);
}

__device__ __forceinline__ float tile_ll(f4 a, int TR, int TC, bool diag,
        int lr, int lg, const float* sq, const uint_t* __restrict__ cnt,
        float lam, float one_m2l) {
    float s = 0.0f;
    #pragma unroll
    for (int q = 0; q < 4; ++q) {
        const int n = TR * 16 + 4 * lg + q;
        const int m = TC * 16 + lr;
        if (!diag || (4 * lg + q) <= lr)
            s += entry_ll(a[q], sq[n], sq[m], cnt[n * 128 + m], lam, one_m2l);
    }
    return s;
}

template<int W>
__device__ __forceinline__ float epi(const f4 (&acc)[9], const float* sq,
        const uint_t* __restrict__ cnt, int lr, int lg, float lam, float one_m2l) {
    constexpr int RA = W, RB = 7 - W;
    float s = 0.0f;
    #pragma unroll
    for (int TC = W; TC < 8; ++TC) {
        s += tile_ll(acc[TC - W], RA, TC, (TC == RA), lr, lg, sq, cnt, lam, one_m2l);
        if (TC >= RB)
            s += tile_ll(acc[TC + 1], RB, TC, (TC == RB), lr, lg, sq, cnt, lam, one_m2l);
    }
    return s;
}

__global__ __launch_bounds__(256, 4) void ll_kernel(
        const uint_t* __restrict__ x_g,
        const float* __restrict__ l_raw, const uint_t* __restrict__ cnt,
        float* __restrict__ sums, int s_base) {
    const int li = blockIdx.x;
    const int s  = s_base + li;
    const int t  = threadIdx.x;

    __shared__ __align__(16) ushort_t Xs[NNODES * 128];   // 32 KB
    __shared__ float sq[NNODES];
    __shared__ float wsum[4];

    const uint_t* gx = x_g + (size_t)li * NNODES * 64;
    const int l = t & 63, w = t >> 6, lr = l & 15, lg = l >> 4;

    // fill LDS (swizzled) with 16B chunks; 2048 chunks over 256 threads
    #pragma unroll
    for (int ii = 0; ii < 8; ++ii) {
        const int i = t + ii * 256;
        const int row = i >> 4, j = i & 15;
        const uint4 v = *(const uint4*)(gx + row * 64 + j * 4);
        const int b = ((row << 8) + (j << 4)) ^ ((row & 7) << 4);
        *(uint4*)((char*)Xs + b) = v;
    }
    __syncthreads();

    f4 acc[9];
    #pragma unroll
    for (int i = 0; i < 9; ++i) acc[i] = (f4)(0.0f);

    switch (w) {
        case 0: gram_w<0>(Xs, acc, lr, lg); write_sq<0>(acc, sq, lr, lg); break;
        case 1: gram_w<1>(Xs, acc, lr, lg); write_sq<1>(acc, sq, lr, lg); break;
        case 2: gram_w<2>(Xs, acc, lr, lg); write_sq<2>(acc, sq, lr, lg); break;
        default: gram_w<3>(Xs, acc, lr, lg); write_sq<3>(acc, sq, lr, lg); break;
    }
    __syncthreads();

    const float lam = 0.06f * normal_cdf_f(l_raw[s]);
    const float one_m2l = 1.0f - 2.0f * lam;
    float ll = 0.0f;
    switch (w) {
        case 0: ll = epi<0>(acc, sq, cnt, lr, lg, lam, one_m2l); break;
        case 1: ll = epi<1>(acc, sq, cnt, lr, lg, lam, one_m2l); break;
        case 2: ll = epi<2>(acc, sq, cnt, lr, lg, lam, one_m2l); break;
        default: ll = epi<3>(acc, sq, cnt, lr, lg, lam, one_m2l); break;
    }

    const float wtot = wave_sum(ll);
    if (l == 0) wsum[w] = wtot;
    __syncthreads();
    if (t == 0) sums[s] = wsum[0] + wsum[1] + wsum[2] + wsum[3];
}

// ---------------------------------------------------------------------------
// Kernel 3: deterministic mean over S
// ---------------------------------------------------------------------------
__global__ __launch_bounds__(256) void reduce_kernel(
        const float* __restrict__ sums, float* __restrict__ out) {
    __shared__ double sh[256];
    const int t = threadIdx.x;
    double acc = 0.0;
    for (int i = t; i < S_TOT; i += 256) acc += (double)sums[i];
    sh[t] = acc;
    __syncthreads();
    for (int off = 128; off > 0; off >>= 1) {
        if (t < off) sh[t] += sh[t + off];
        __syncthreads();
    }
    if (t == 0) out[0] = (float)(sh[0] / (double)S_TOT);
}

// ---------------------------------------------------------------------------
extern "C" void kernel_launch(void* const* d_in, const int* in_sizes, int n_in,
                              void* d_out, int out_size, void* d_ws, size_t ws_size,
                              hipStream_t stream) {
    (void)in_sizes; (void)n_in; (void)out_size;
    const float* d_raw = (const float*)d_in[0];
    const float* c_raw = (const float*)d_in[1];
    const float* a_raw = (const float*)d_in[2];
    const float* l_raw = (const float*)d_in[3];
    const int*   all_t = (const int*)d_in[4];
    const int*   cor_t = (const int*)d_in[5];
    float* out = (float*)d_out;

    char*   ws   = (char*)d_ws;
    float*  sums = (float*)ws;                        // 8 KB
    uint_t* cnt  = (uint_t*)(ws + 8192);              // 64 KB packed counts
    char*   xbase = ws + 8192 + 65536;
    const size_t per_sample = (size_t)NNODES * 64 * sizeof(uint_t);  // 32 KB

    const size_t head = 8192 + 65536;
    size_t avail = (ws_size > head) ? ws_size - head : 0;
    int chunk = (int)(avail / per_sample);
    if (chunk > S_TOT) chunk = S_TOT;
    if (chunk < 1) chunk = 1;

    prep_counts<<<64, 256, 0, stream>>>(all_t, cor_t, cnt);

    for (int s0 = 0; s0 < S_TOT; s0 += chunk) {
        const int nblk = (S_TOT - s0 < chunk) ? (S_TOT - s0) : chunk;
        uint_t* xbuf = (uint_t*)xbase;
        traj_kernel<<<nblk, 64, 0, stream>>>(d_raw, c_raw, a_raw, xbuf, s0);
        ll_kernel<<<nblk, 256, 0, stream>>>(xbuf, l_raw, cnt, sums, s0);
    }
    reduce_kernel<<<1, 256, 0, stream>>>(sums, out);
}

// Round 9
// 100.357 us; speedup vs baseline: 6.5874x; 1.0899x over previous
//
#include <hip/hip_runtime.h>
#include <math.h>

#define S_TOT   2048
#define NNODES  128
#define D_DIM   127
#define N_STEPS 126

typedef unsigned short ushort_t;
typedef unsigned int   uint_t;
typedef __attribute__((ext_vector_type(8))) short bfrag;   // 8 bf16 = 4 VGPR
typedef __attribute__((ext_vector_type(4))) float f4;

__device__ __forceinline__ float softplus_f(float x) {
    return log1pf(expf(-fabsf(x))) + fmaxf(x, 0.0f);
}
__device__ __forceinline__ float normal_cdf_f(float x) {
    return 0.5f * (1.0f + erff(x * 0.7071067811865475f));
}
__device__ __forceinline__ float frl(float x, int lane) {
    return __int_as_float(__builtin_amdgcn_readlane(__float_as_int(x), lane));
}
// 64-lane sum via DPP; returns wave-uniform total.
__device__ __forceinline__ float wave_sum(float x) {
    float r = x; int v;
    v = __builtin_amdgcn_update_dpp(0, __float_as_int(r), 0x111, 0xf, 0xf, true); r += __int_as_float(v);
    v = __builtin_amdgcn_update_dpp(0, __float_as_int(r), 0x112, 0xf, 0xf, true); r += __int_as_float(v);
    v = __builtin_amdgcn_update_dpp(0, __float_as_int(r), 0x114, 0xf, 0xf, true); r += __int_as_float(v);
    v = __builtin_amdgcn_update_dpp(0, __float_as_int(r), 0x118, 0xf, 0xf, true); r += __int_as_float(v);
    v = __builtin_amdgcn_update_dpp(0, __float_as_int(r), 0x142, 0xa, 0xf, true); r += __int_as_float(v);
    v = __builtin_amdgcn_update_dpp(0, __float_as_int(r), 0x143, 0xc, 0xf, true); r += __int_as_float(v);
    return frl(r, 63);
}
__device__ __forceinline__ ushort_t f2bf(float x) {        // RNE fp32 -> bf16
    uint_t u = __float_as_uint(x);
    uint_t r = u + 0x7fffu + ((u >> 16) & 1u);
    return (ushort_t)(r >> 16);
}
__device__ __forceinline__ float bf2f(ushort_t h) {
    return __uint_as_float(((uint_t)h) << 16);
}

// ---------------------------------------------------------------------------
// Kernel 0: symmetrized counts packed as bf16 pair: lo = csym, hi = asym-csym
// ---------------------------------------------------------------------------
__global__ __launch_bounds__(256) void prep_counts(
        const int* __restrict__ all_t, const int* __restrict__ cor_t,
        uint_t* __restrict__ pk) {
    int i = blockIdx.x * 256 + threadIdx.x;       // 16384
    int n = i >> 7, m = i & 127;
    int at = all_t[i], ct = cor_t[i];
    if (n != m) { at += all_t[m * 128 + n]; ct += cor_t[m * 128 + n]; }
    pk[i] = (uint_t)f2bf((float)ct) | ((uint_t)f2bf((float)(at - ct)) << 16);
}

// ---------------------------------------------------------------------------
// Kernel 1: trajectory. One wave per sample; lane l owns dims 2l, 2l+1.
// Structure identical to round 8. ONE change: amdgpu_waves_per_eu(1,2)
// gives the register allocator a 256-VGPR budget (grid supplies only
// 2 waves/SIMD anyway), so the compiler stops re-serializing the
// software pipeline to hit a 64-VGPR/8-wave occupancy target it can
// never use (round-8 evidence: VGPR=68 for ~110 live values).
// ---------------------------------------------------------------------------
#define LDR1(A, B, row)                                                       \
    { const float* _p = ap + (size_t)(row) * D_DIM + 2 * lane;                \
      A = _p[0];                                                              \
      float _t = _p[d1ok ? 1 : 0];   /* lane63 stays in-bounds */             \
      B = d1ok ? _t : 0.0f; }

#define LOAD_G(BASE, GUARD)                                                   \
    { const int _b = (BASE); const bool _gd = (GUARD);                        \
      if (!_gd || _b + 0  < 126) LDR1(sa0,  sb0,  _b + 0)  else { sa0 = 0; sb0 = 0; }   \
      if (!_gd || _b + 1  < 126) LDR1(sa1,  sb1,  _b + 1)  else { sa1 = 0; sb1 = 0; }   \
      if (!_gd || _b + 2  < 126) LDR1(sa2,  sb2,  _b + 2)  else { sa2 = 0; sb2 = 0; }   \
      if (!_gd || _b + 3  < 126) LDR1(sa3,  sb3,  _b + 3)  else { sa3 = 0; sb3 = 0; }   \
      if (!_gd || _b + 4  < 126) LDR1(sa4,  sb4,  _b + 4)  else { sa4 = 0; sb4 = 0; }   \
      if (!_gd || _b + 5  < 126) LDR1(sa5,  sb5,  _b + 5)  else { sa5 = 0; sb5 = 0; }   \
      if (!_gd || _b + 6  < 126) LDR1(sa6,  sb6,  _b + 6)  else { sa6 = 0; sb6 = 0; }   \
      if (!_gd || _b + 7  < 126) LDR1(sa7,  sb7,  _b + 7)  else { sa7 = 0; sb7 = 0; }   \
      if (!_gd || _b + 8  < 126) LDR1(sa8,  sb8,  _b + 8)  else { sa8 = 0; sb8 = 0; }   \
      if (!_gd || _b + 9  < 126) LDR1(sa9,  sb9,  _b + 9)  else { sa9 = 0; sb9 = 0; }   \
      if (!_gd || _b + 10 < 126) LDR1(sa10, sb10, _b + 10) else { sa10 = 0; sb10 = 0; } \
      if (!_gd || _b + 11 < 126) LDR1(sa11, sb11, _b + 11) else { sa11 = 0; sb11 = 0; } \
      if (!_gd || _b + 12 < 126) LDR1(sa12, sb12, _b + 12) else { sa12 = 0; sb12 = 0; } \
      if (!_gd || _b + 13 < 126) LDR1(sa13, sb13, _b + 13) else { sa13 = 0; sb13 = 0; } \
      if (!_gd || _b + 14 < 126) LDR1(sa14, sb14, _b + 14) else { sa14 = 0; sb14 = 0; } \
      if (!_gd || _b + 15 < 126) LDR1(sa15, sb15, _b + 15) else { sa15 = 0; sb15 = 0; } }

#define WRITE_G(SB)                                                           \
    { const int _s = (SB);                                                    \
      *(float2*)&abuf[_s + 0 ][2 * lane] = make_float2(sa0,  sb0);            \
      *(float2*)&abuf[_s + 1 ][2 * lane] = make_float2(sa1,  sb1);            \
      *(float2*)&abuf[_s + 2 ][2 * lane] = make_float2(sa2,  sb2);            \
      *(float2*)&abuf[_s + 3 ][2 * lane] = make_float2(sa3,  sb3);            \
      *(float2*)&abuf[_s + 4 ][2 * lane] = make_float2(sa4,  sb4);            \
      *(float2*)&abuf[_s + 5 ][2 * lane] = make_float2(sa5,  sb5);            \
      *(float2*)&abuf[_s + 6 ][2 * lane] = make_float2(sa6,  sb6);            \
      *(float2*)&abuf[_s + 7 ][2 * lane] = make_float2(sa7,  sb7);            \
      *(float2*)&abuf[_s + 8 ][2 * lane] = make_float2(sa8,  sb8);            \
      *(float2*)&abuf[_s + 9 ][2 * lane] = make_float2(sa9,  sb9);            \
      *(float2*)&abuf[_s + 10][2 * lane] = make_float2(sa10, sb10);           \
      *(float2*)&abuf[_s + 11][2 * lane] = make_float2(sa11, sb11);           \
      *(float2*)&abuf[_s + 12][2 * lane] = make_float2(sa12, sb12);           \
      *(float2*)&abuf[_s + 13][2 * lane] = make_float2(sa13, sb13);           \
      *(float2*)&abuf[_s + 14][2 * lane] = make_float2(sa14, sb14);           \
      *(float2*)&abuf[_s + 15][2 * lane] = make_float2(sa15, sb15); }

// SC: ring slot of current row; SA: slot of row i+2 (aa/aE precompute);
// SR: slot to refill with row i+3; ROWRD: abuf row index for the refill;
// CLSI/DLSI: cos-sin / dstep lookahead indices.
#define STEP_CORE(SC, SA, SR, ROWRD, CLSI, DLSI)                              \
    {                                                                         \
        const float ca = ra_r[SC], cb = rb_r[SC];                             \
        /* --- inter-step critical chain --- */                               \
        float va = wave_sum(fmaf(v0, ca, v1 * cb));                           \
        float ua = fmaf(fmaf(-vp0, aE0U, va), rcp_v, aE0U);                   \
        float w1 = fmaf(-ua, vp1s, aE1U);                                     \
        float inv = __builtin_amdgcn_rsqf(fmaf(-va, va, aaU));                \
        float invs = (w1 >= 0.0f) ? -inv : inv;                               \
        float sf = sU * invs;                                                 \
        float nv0 = fmaf(cU, v0, sf * fmaf(-va, v0, ca));                     \
        float nv1 = fmaf(cU, v1, sf * fmaf(-va, v1, cb));                     \
        float np0 = fmaf(cU, vp0, sf * fmaf(-va, vp0, aE0U));                 \
        float np1 = fmaf(cU, vp1, sf * fmaf(-va, vp1, aE1U));                 \
        v0 = nv0; v1 = nv1; vp0 = np0; vp1 = np1;                             \
        { float ns = copysignf(1.0f, vp0);                                    \
          rcp_v = __builtin_amdgcn_rcpf(vp0 + ns); vp1s = vp1 * ns; }         \
        x0 = fmaf(dU, v0, x0); x1 = fmaf(dU, v1, x1);                         \
        { uint_t pk;                                                          \
          asm("v_cvt_pk_bf16_f32 %0, %1, %2" : "=v"(pk) : "v"(x0), "v"(x1));  \
          xp += 64; xp[lane] = pk; }                                          \
        /* --- off-chain: shift + refill pipelines --- */                     \
        aaU = aa1; aE0U = aE0_1; aE1U = aE1_1; cU = c1; sU = s1; dU = d1;     \
        aa1 = wave_sum(fmaf(ra_r[SA], ra_r[SA], rb_r[SA] * rb_r[SA]));        \
        aE0_1 = frl(ra_r[SA], 0); aE1_1 = frl(rb_r[SA], 0);                   \
        { float2 cs = cls2[CLSI]; c1 = cs.x; s1 = cs.y; }                     \
        d1 = dls[DLSI];                                                       \
        { float2 nx = *(float2*)&abuf[ROWRD][2 * lane];                       \
          ra_r[SR] = nx.x; rb_r[SR] = nx.y; }                                 \
    }

#define MSTEP(J) STEP_CORE((J) & 3, ((J) + 2) & 3, ((J) + 3) & 3,             \
                           (ib + (J) + 3) & 31, ib + (J) + 2, ib + (J) + 3)
#define TSTEP(J) STEP_CORE((J) & 3, ((J) + 2) & 3, ((J) + 3) & 3,             \
                           ((115 + (J) < 125) ? (115 + (J)) : 125) & 31,      \
                           ((114 + (J) < 127) ? (114 + (J)) : 127),           \
                           ((115 + (J) < 127) ? (115 + (J)) : 127))

__global__
__attribute__((amdgpu_flat_work_group_size(64, 64), amdgpu_waves_per_eu(1, 2)))
void traj_kernel(
        const float* __restrict__ d_raw, const float* __restrict__ c_raw,
        const float* __restrict__ a_raw,
        uint_t* __restrict__ xout, int s_base) {
    const int li = blockIdx.x;
    const int s  = s_base + li;
    const int lane = threadIdx.x;
    const bool d1ok = lane < 63;                  // dim 2l+1 <= 126

    __shared__ __align__(16) float abuf[32][128]; // 16 KB (2 groups x 16 rows)
    __shared__ float  dls[128];
    __shared__ float2 cls2[128];

    // d (softplus'd), cos/sin tables for uniform broadcast reads (padded 0)
    float t0 = softplus_f(d_raw[(size_t)s * D_DIM + lane]);
    dls[lane] = t0;
    dls[64 + lane] = d1ok ? softplus_f(d_raw[(size_t)s * D_DIM + 64 + lane]) : 0.0f;
    {
        float cv = c_raw[(size_t)s * N_STEPS + lane];
        cls2[lane] = make_float2(__cosf(cv), __sinf(cv));
        if (lane < 62) {
            float cv2 = c_raw[(size_t)s * N_STEPS + 64 + lane];
            cls2[64 + lane] = make_float2(__cosf(cv2), __sinf(cv2));
        } else {
            cls2[64 + lane] = make_float2(0.0f, 0.0f);
        }
    }

    const float* ap = a_raw + (size_t)s * N_STEPS * D_DIM;

    // staging regs: one 16-row group
    float sa0, sa1, sa2, sa3, sa4, sa5, sa6, sa7,
          sa8, sa9, sa10, sa11, sa12, sa13, sa14, sa15;
    float sb0, sb1, sb2, sb3, sb4, sb5, sb6, sb7,
          sb8, sb9, sb10, sb11, sb12, sb13, sb14, sb15;

    // prologue: G0,G1 staged+written; G2 loaded (written at B_0)
    LOAD_G(0, false)  WRITE_G(0)
    LOAD_G(16, false) WRITE_G(16)
    LOAD_G(32, false)

    // ring (rows i..i+3) + pipelines primed for steps 0,1
    float ra_r[4], rb_r[4];
    { float2 t = *(float2*)&abuf[0][2 * lane]; ra_r[0] = t.x; rb_r[0] = t.y; }
    { float2 t = *(float2*)&abuf[1][2 * lane]; ra_r[1] = t.x; rb_r[1] = t.y; }
    { float2 t = *(float2*)&abuf[2][2 * lane]; ra_r[2] = t.x; rb_r[2] = t.y; }
    ra_r[3] = 0.0f; rb_r[3] = 0.0f;
    float aaU = wave_sum(fmaf(ra_r[0], ra_r[0], rb_r[0] * rb_r[0]));
    float aa1 = wave_sum(fmaf(ra_r[1], ra_r[1], rb_r[1] * rb_r[1]));
    float aE0U = frl(ra_r[0], 0), aE1U = frl(rb_r[0], 0);
    float aE0_1 = frl(ra_r[1], 0), aE1_1 = frl(rb_r[1], 0);
    float cU, sU, c1, s1;
    { float2 cs = cls2[0]; cU = cs.x; sU = cs.y; }
    { float2 cs = cls2[1]; c1 = cs.x; s1 = cs.y; }
    float dU = dls[1], d1 = dls[2];

    // state: v (lane dims), replicated pivots, x
    float v0 = (lane == 0) ? 1.0f : 0.0f, v1 = 0.0f;
    float vp0 = 1.0f, vp1 = 0.0f, vp1s = 0.0f, rcp_v = 0.5f;
    float x0 = (lane == 0) ? t0 : 0.0f, x1 = 0.0f;

    uint_t* xp = xout + (size_t)li * NNODES * 64;
    xp[lane] = 0u;                                // row 0
    {
        uint_t pk0;
        asm("v_cvt_pk_bf16_f32 %0, %1, %2" : "=v"(pk0) : "v"(x0), "v"(x1));
        xp += 64; xp[lane] = pk0;                 // row 1
    }

    // main: 7 groups x 16 steps (i = 0..111)
    #pragma unroll 1
    for (int g = 0; g < 7; ++g) {
        const int ib = g << 4;
        MSTEP(0)  MSTEP(1)  MSTEP(2)  MSTEP(3)
        MSTEP(4)  MSTEP(5)  MSTEP(6)  MSTEP(7)
        MSTEP(8)  MSTEP(9)  MSTEP(10) MSTEP(11)
        MSTEP(12) MSTEP(13) MSTEP(14) MSTEP(15)
        if (g <= 5) { WRITE_G((g & 1) << 4) }     // write G_{g+2}
        if (g <= 4) LOAD_G((g + 3) << 4, g == 4)  // load  G_{g+3}
    }
    // tail: steps 112..125
    TSTEP(0)  TSTEP(1)  TSTEP(2)  TSTEP(3)
    TSTEP(4)  TSTEP(5)  TSTEP(6)  TSTEP(7)
    TSTEP(8)  TSTEP(9)  TSTEP(10) TSTEP(11)
    TSTEP(12) TSTEP(13)
}
#undef MSTEP
#undef TSTEP
#undef STEP_CORE
#undef LOAD_G
#undef WRITE_G
#undef LDR1

// ---------------------------------------------------------------------------
// Kernel 2: MFMA gram (single 32KB bf16 LDS stage) + B-S tail log-lik.
// 4 waves; wave w owns tile-rows {w, 7-w} via template<int W> (acc = 9 f4).
// ---------------------------------------------------------------------------
__device__ __forceinline__ bfrag ldfrag(const ushort_t* base, int row, int kelem) {
    int byte = ((row << 8) + (kelem << 1)) ^ ((row & 7) << 4);
    return *(const bfrag*)((const char*)base + byte);
}

template<int W>
__device__ __forceinline__ void gram_w(const ushort_t* Xs, f4 (&acc)[9],
                                       int lr, int lg) {
    constexpr int RA = W, RB = 7 - W;
    #pragma unroll
    for (int ks = 0; ks < 4; ++ks) {
        const int kb = ks * 32 + lg * 8;
        const bfrag ha = ldfrag(Xs, RA * 16 + lr, kb);
        const bfrag hb = ldfrag(Xs, RB * 16 + lr, kb);
        #pragma unroll
        for (int TC = W; TC < 8; ++TC) {
            const bfrag bh = ldfrag(Xs, TC * 16 + lr, kb);
            acc[TC - W] = __builtin_amdgcn_mfma_f32_16x16x32_bf16(ha, bh, acc[TC - W], 0, 0, 0);
            if (TC >= RB)
                acc[TC + 1] = __builtin_amdgcn_mfma_f32_16x16x32_bf16(hb, bh, acc[TC + 1], 0, 0, 0);
        }
    }
}

template<int W>
__device__ __forceinline__ void write_sq(const f4 (&acc)[9], float* sq, int lr, int lg) {
    #pragma unroll
    for (int q = 0; q < 4; ++q) {
        if (4 * lg + q == lr) {
            sq[W * 16 + lr]       = acc[0][q];       // tile (W,W)
            sq[(7 - W) * 16 + lr] = acc[8 - W][q];   // tile (7-W,7-W)
        }
    }
}

// Borjesson-Sundberg Q(z) ~ phi(z)/((1-A)z + A*sqrt(z^2+B)); rel err <~0.5%.
// q_axb = F1 + F2 - 2 F1 F2 is relative-accurate (no cancellation).
__device__ __forceinline__ float entry_ll(float g, float sqn, float sqm,
        uint_t cw, float lam, float one_m2l) {
    const float d2 = fmaxf(sqn + sqm - 2.0f * g, 0.0f);
    const float pd = __builtin_amdgcn_sqrtf(d2);
    const float A = 0.344f, B = 5.334f, IA = 0.656f, C = 0.3989422804f;
    const float z1 = 0.70710678f * pd, z2 = 0.5f * pd;
    const float e1 = __expf(-0.25f  * d2) * C;   // phi(z1)
    const float e2 = __expf(-0.125f * d2) * C;   // phi(z2)
    const float den1 = fmaf(A, __builtin_amdgcn_sqrtf(fmaf(0.5f,  d2, B)), IA * z1);
    const float den2 = fmaf(A, __builtin_amdgcn_sqrtf(fmaf(0.25f, d2, B)), IA * z2);
    const float F1 = e1 * __builtin_amdgcn_rcpf(den1);
    const float F2 = e2 * __builtin_amdgcn_rcpf(den2);
    const float qax = F1 + F2 - 2.0f * F1 * F2;
    float qp = fmaf(one_m2l, qax, lam);
    qp = fminf(fmaxf(qp, 1e-7f), 1.0f - 1e-7f);
    const float pp = 1.0f - qp;
    const float c   = bf2f((ushort_t)(cw & 0xffffu));
    const float amc = bf2f((ushort_t)(cw >> 16));
    return c * __logf(pp) + amc * __logf(qp);
}

__device__ __forceinline__ float tile_ll(f4 a, int TR, int TC, bool diag,
        int lr, int lg, const float* sq, const uint_t* __restrict__ cnt,
        float lam, float one_m2l) {
    float s = 0.0f;
    #pragma unroll
    for (int q = 0; q < 4; ++q) {
        const int n = TR * 16 + 4 * lg + q;
        const int m = TC * 16 + lr;
        if (!diag || (4 * lg + q) <= lr)
            s += entry_ll(a[q], sq[n], sq[m], cnt[n * 128 + m], lam, one_m2l);
    }
    return s;
}

template<int W>
__device__ __forceinline__ float epi(const f4 (&acc)[9], const float* sq,
        const uint_t* __restrict__ cnt, int lr, int lg, float lam, float one_m2l) {
    constexpr int RA = W, RB = 7 - W;
    float s = 0.0f;
    #pragma unroll
    for (int TC = W; TC < 8; ++TC) {
        s += tile_ll(acc[TC - W], RA, TC, (TC == RA), lr, lg, sq, cnt, lam, one_m2l);
        if (TC >= RB)
            s += tile_ll(acc[TC + 1], RB, TC, (TC == RB), lr, lg, sq, cnt, lam, one_m2l);
    }
    return s;
}

__global__ __launch_bounds__(256, 4) void ll_kernel(
        const uint_t* __restrict__ x_g,
        const float* __restrict__ l_raw, const uint_t* __restrict__ cnt,
        float* __restrict__ sums, int s_base) {
    const int li = blockIdx.x;
    const int s  = s_base + li;
    const int t  = threadIdx.x;

    __shared__ __align__(16) ushort_t Xs[NNODES * 128];   // 32 KB
    __shared__ float sq[NNODES];
    __shared__ float wsum[4];

    const uint_t* gx = x_g + (size_t)li * NNODES * 64;
    const int l = t & 63, w = t >> 6, lr = l & 15, lg = l >> 4;

    // fill LDS (swizzled) with 16B chunks; 2048 chunks over 256 threads
    #pragma unroll
    for (int ii = 0; ii < 8; ++ii) {
        const int i = t + ii * 256;
        const int row = i >> 4, j = i & 15;
        const uint4 v = *(const uint4*)(gx + row * 64 + j * 4);
        const int b = ((row << 8) + (j << 4)) ^ ((row & 7) << 4);
        *(uint4*)((char*)Xs + b) = v;
    }
    __syncthreads();

    f4 acc[9];
    #pragma unroll
    for (int i = 0; i < 9; ++i) acc[i] = (f4)(0.0f);

    switch (w) {
        case 0: gram_w<0>(Xs, acc, lr, lg); write_sq<0>(acc, sq, lr, lg); break;
        case 1: gram_w<1>(Xs, acc, lr, lg); write_sq<1>(acc, sq, lr, lg); break;
        case 2: gram_w<2>(Xs, acc, lr, lg); write_sq<2>(acc, sq, lr, lg); break;
        default: gram_w<3>(Xs, acc, lr, lg); write_sq<3>(acc, sq, lr, lg); break;
    }
    __syncthreads();

    const float lam = 0.06f * normal_cdf_f(l_raw[s]);
    const float one_m2l = 1.0f - 2.0f * lam;
    float ll = 0.0f;
    switch (w) {
        case 0: ll = epi<0>(acc, sq, cnt, lr, lg, lam, one_m2l); break;
        case 1: ll = epi<1>(acc, sq, cnt, lr, lg, lam, one_m2l); break;
        case 2: ll = epi<2>(acc, sq, cnt, lr, lg, lam, one_m2l); break;
        default: ll = epi<3>(acc, sq, cnt, lr, lg, lam, one_m2l); break;
    }

    const float wtot = wave_sum(ll);
    if (l == 0) wsum[w] = wtot;
    __syncthreads();
    if (t == 0) sums[s] = wsum[0] + wsum[1] + wsum[2] + wsum[3];
}

// ---------------------------------------------------------------------------
// Kernel 3: deterministic mean over S
// ---------------------------------------------------------------------------
__global__ __launch_bounds__(256) void reduce_kernel(
        const float* __restrict__ sums, float* __restrict__ out) {
    __shared__ double sh[256];
    const int t = threadIdx.x;
    double acc = 0.0;
    for (int i = t; i < S_TOT; i += 256) acc += (double)sums[i];
    sh[t] = acc;
    __syncthreads();
    for (int off = 128; off > 0; off >>= 1) {
        if (t < off) sh[t] += sh[t + off];
        __syncthreads();
    }
    if (t == 0) out[0] = (float)(sh[0] / (double)S_TOT);
}

// ---------------------------------------------------------------------------
extern "C" void kernel_launch(void* const* d_in, const int* in_sizes, int n_in,
                              void* d_out, int out_size, void* d_ws, size_t ws_size,
                              hipStream_t stream) {
    (void)in_sizes; (void)n_in; (void)out_size;
    const float* d_raw = (const float*)d_in[0];
    const float* c_raw = (const float*)d_in[1];
    const float* a_raw = (const float*)d_in[2];
    const float* l_raw = (const float*)d_in[3];
    const int*   all_t = (const int*)d_in[4];
    const int*   cor_t = (const int*)d_in[5];
    float* out = (float*)d_out;

    char*   ws   = (char*)d_ws;
    float*  sums = (float*)ws;                        // 8 KB
    uint_t* cnt  = (uint_t*)(ws + 8192);              // 64 KB packed counts
    char*   xbase = ws + 8192 + 65536;
    const size_t per_sample = (size_t)NNODES * 64 * sizeof(uint_t);  // 32 KB

    const size_t head = 8192 + 65536;
    size_t avail = (ws_size > head) ? ws_size - head : 0;
    int chunk = (int)(avail / per_sample);
    if (chunk > S_TOT) chunk = S_TOT;
    if (chunk < 1) chunk = 1;

    prep_counts<<<64, 256, 0, stream>>>(all_t, cor_t, cnt);

    for (int s0 = 0; s0 < S_TOT; s0 += chunk) {
        const int nblk = (S_TOT - s0 < chunk) ? (S_TOT - s0) : chunk;
        uint_t* xbuf = (uint_t*)xbase;
        traj_kernel<<<nblk, 64, 0, stream>>>(d_raw, c_raw, a_raw, xbuf, s0);
        ll_kernel<<<nblk, 256, 0, stream>>>(xbuf, l_raw, cnt, sums, s0);
    }
    reduce_kernel<<<1, 256, 0, stream>>>(sums, out);
}